// Round 19
// baseline (4541.180 us; speedup 1.0000x reference)
//
#include <hip/hip_runtime.h>
#include <cstddef>

#define NGRAPH 1000
#define NEDGES 1600000
#define DD     300
#define DD2    600
#define DIN    128
#define NLAYER 5
#define NCLS   10
#define BR     32
#define BRM    32

// MFMA fragment geometry
#define NT2 38
#define NK2 10
#define NT3 19
#define NK3 19
#define WFRAG 1024
#define W1F_SZ (NT2*NK2*WFRAG)

typedef unsigned short u16;
typedef unsigned char  u8;
typedef unsigned int   u32;
typedef __attribute__((ext_vector_type(8))) short short8;
typedef __attribute__((ext_vector_type(4))) short short4v;
typedef __attribute__((ext_vector_type(4))) float f32x4;

// ---------------- bf16 helpers ----------------------------------------------
__device__ __forceinline__ u16 f2bf(float f) {
    u32 u; __builtin_memcpy(&u, &f, 4);
    u = (u + 0x7FFFu + ((u >> 16) & 1u)) >> 16;
    return (u16)u;
}
__device__ __forceinline__ float bf2f(u16 h) {
    u32 u = ((u32)h) << 16;
    float f; __builtin_memcpy(&f, &u, 4); return f;
}

// ---------------- fp24 storage helpers (hi u16 plane + lo u8 plane) --------
__device__ __forceinline__ float ld24(const u16* __restrict__ hi, const u8* __restrict__ lo,
                                      size_t idx) {
    u32 u = ((u32)hi[idx] << 16) | ((u32)lo[idx] << 8);
    float f; __builtin_memcpy(&f, &u, 4); return f;
}
__device__ __forceinline__ void st24(u16* __restrict__ hi, u8* __restrict__ lo,
                                     size_t idx, float f) {
    u32 u; __builtin_memcpy(&u, &f, 4);
    u32 r = u + 0x7Fu + ((u >> 8) & 1u);
    hi[idx] = (u16)(r >> 16); lo[idx] = (u8)(r >> 8);
}
__device__ __forceinline__ void ld24x4(const u16* __restrict__ hi, const u8* __restrict__ lo,
                                       size_t idx, float o[4]) {
    ushort4 h = *(const ushort4*)(hi + idx);
    uchar4  l = *(const uchar4*)(lo + idx);
    u32 u0 = ((u32)h.x << 16) | ((u32)l.x << 8);
    u32 u1 = ((u32)h.y << 16) | ((u32)l.y << 8);
    u32 u2 = ((u32)h.z << 16) | ((u32)l.z << 8);
    u32 u3 = ((u32)h.w << 16) | ((u32)l.w << 8);
    __builtin_memcpy(&o[0], &u0, 4); __builtin_memcpy(&o[1], &u1, 4);
    __builtin_memcpy(&o[2], &u2, 4); __builtin_memcpy(&o[3], &u3, 4);
}
__device__ __forceinline__ void st24x4(u16* __restrict__ hi, u8* __restrict__ lo,
                                       size_t idx, const float v[4]) {
    u32 u[4];
#pragma unroll
    for (int q = 0; q < 4; ++q) {
        u32 t; __builtin_memcpy(&t, &v[q], 4);
        u[q] = t + 0x7Fu + ((t >> 8) & 1u);
    }
    ushort4 h; h.x = (u16)(u[0] >> 16); h.y = (u16)(u[1] >> 16);
    h.z = (u16)(u[2] >> 16); h.w = (u16)(u[3] >> 16);
    uchar4 l8; l8.x = (u8)(u[0] >> 8); l8.y = (u8)(u[1] >> 8);
    l8.z = (u8)(u[2] >> 8); l8.w = (u8)(u[3] >> 8);
    *(ushort4*)(hi + idx) = h;
    *(uchar4*)(lo + idx) = l8;
}

// ---------------------------------------------------------------------------
__global__ void diag_kernel(float* __restrict__ out, int n, float val)
{
    int i = blockIdx.x * 256 + threadIdx.x;
    if (i < n) out[i] = val;
}

__global__ void vn_init_kernel(float* __restrict__ vn, const float* __restrict__ vn0)
{
    int idx = blockIdx.x * 256 + threadIdx.x;
    if (idx < NGRAPH * DD) vn[idx] = vn0[idx % DD];
}

__global__ void bconv_kernel(const int* __restrict__ braw, int n, int* __restrict__ b32)
{
    int i = blockIdx.x * 256 + threadIdx.x;
    if (i >= n) return;
    int fs = (braw[n - 1] == 0) ? 2 : 1;
    b32[i] = braw[(size_t)i * fs];
}

// pack W [K x N] fp32 -> MFMA B-fragments, split bf16 hi/lo.
__global__ void packW_kernel(const float* __restrict__ W, int K, int N,
                             int nT, int nK, short* __restrict__ dst)
{
    int idx = blockIdx.x * 256 + threadIdx.x;
    int total = nT * nK * 64;
    if (idx >= total) return;
    int lane = idx & 63;
    int tk = idx >> 6;
    int nn = (tk / nK) * 16 + (lane & 15);
    int k0 = (tk % nK) * 32 + (lane >> 4) * 8;
    short* o = dst + ((size_t)tk << 10) + lane * 8;
#pragma unroll
    for (int j = 0; j < 8; ++j) {
        float v = (nn < N && (k0 + j) < K) ? W[(size_t)(k0 + j) * N + nn] : 0.f;
        u16 h = f2bf(v);
        o[j] = (short)h;
        o[512 + j] = (short)f2bf(v - bf2f(h));
    }
}

// ---------------- CSR build -------------------------------------------------
__global__ void deg_kernel(const int* __restrict__ ei, int fe, int E, int* __restrict__ deg)
{
    int e = blockIdx.x * 256 + threadIdx.x;
    if (e < E) atomicAdd(&deg[ei[(size_t)fe * (E + e)]], 1);
}

__global__ void scan_kernel(const int* __restrict__ deg, int* __restrict__ row_ptr, int n)
{
    __shared__ int sd[1024];
    int t = threadIdx.x;
    int C = (n + 1023) >> 10;
    int i0 = t * C, i1 = i0 + C; if (i1 > n) i1 = n; if (i0 > n) i0 = n;
    int s = 0;
    for (int i = i0; i < i1; ++i) s += deg[i];
    sd[t] = s;
    __syncthreads();
    for (int o = 1; o < 1024; o <<= 1) {
        int x = (t >= o) ? sd[t - o] : 0;
        __syncthreads();
        sd[t] += x;
        __syncthreads();
    }
    int run = (t == 0) ? 0 : sd[t - 1];
    for (int i = i0; i < i1; ++i) { row_ptr[i] = run; run += deg[i]; }
    if (t == 1023) row_ptr[n] = sd[1023];
}

__global__ void scatter_kernel(const int* __restrict__ ei, int fe, int E,
                               int* __restrict__ cursor, int* __restrict__ col_idx)
{
    int e = blockIdx.x * 256 + threadIdx.x;
    if (e < E) {
        int d = ei[(size_t)fe * (E + e)];
        int s = ei[(size_t)fe * e];
        int p = atomicAdd(&cursor[d], 1);
        col_idx[p] = s;
    }
}

__device__ __forceinline__ int lower_bound_i(const int* __restrict__ arr, int n, int key)
{
    int lo = 0, hi = n;
    while (lo < hi) {
        int mid = (lo + hi) >> 1;
        if (arr[mid] < key) lo = mid + 1; else hi = mid;
    }
    return lo;
}

// ---------------- vtmp[g] = segment_sum(hl) + vn  (row-unrolled x4) ----------
__global__ void vtmp_kernel(const u16* __restrict__ hi, const u8* __restrict__ lo,
                            const int* __restrict__ batch, const float* __restrict__ vn,
                            float* __restrict__ vtmp, int n)
{
    int g = blockIdx.x, t = threadIdx.x;
    int l0 = lower_bound_i(batch, n, g);
    int h0 = lower_bound_i(batch, n, g + 1);
    if (t >= DD) return;
    float a0 = 0.f, a1 = 0.f, a2 = 0.f, a3 = 0.f;
    int i = l0;
    for (; i + 3 < h0; i += 4) {
        a0 += ld24(hi, lo, (size_t)(i + 0) * DD + t);
        a1 += ld24(hi, lo, (size_t)(i + 1) * DD + t);
        a2 += ld24(hi, lo, (size_t)(i + 2) * DD + t);
        a3 += ld24(hi, lo, (size_t)(i + 3) * DD + t);
    }
    for (; i < h0; ++i) a0 += ld24(hi, lo, (size_t)i * DD + t);
    vtmp[(size_t)g * DD + t] = ((a0 + a1) + (a2 + a3)) + vn[(size_t)g * DD + t];
}

// ---------------- fused vn MLP ----------------------------------------------
__global__ void vn_mlp_kernel(const float* __restrict__ vtmp,
                              const float* __restrict__ W1, const float* __restrict__ b1,
                              const float* __restrict__ s1, const float* __restrict__ sb1,
                              const float* __restrict__ W2, const float* __restrict__ b2,
                              const float* __restrict__ s2, const float* __restrict__ sb2,
                              float* __restrict__ vn)
{
    __shared__ float vt[DD];
    __shared__ float us[DD2];
    int g = blockIdx.x, t = threadIdx.x;
    if (t < DD) vt[t] = vtmp[(size_t)g * DD + t];
    __syncthreads();
    for (int j = t; j < DD2; j += 512) {
        float acc = 0.f;
        for (int k = 0; k < DD; ++k) acc = fmaf(vt[k], W1[(size_t)k * DD2 + j], acc);
        us[j] = fmaxf(fmaf(acc + b1[j], s1[j], sb1[j]), 0.f);
    }
    __syncthreads();
    for (int j = t; j < DD; j += 512) {
        float acc = 0.f;
        for (int k = 0; k < DD2; ++k) acc = fmaf(us[k], W2[(size_t)k * DD + j], acc);
        vn[(size_t)g * DD + j] = fmaxf(fmaf(acc + b2[j], s2[j], sb2[j]), 0.f);
    }
}

// ---------------- encoder (writes h0 = hl0 since vn0 = 0) --------------------
__global__ __launch_bounds__(1024)
void encoder_kernel(const float* __restrict__ x, const float* __restrict__ W,
                    const float* __restrict__ b,
                    u16* __restrict__ Ahi, u8* __restrict__ Alo,
                    short* __restrict__ NRm, float* __restrict__ NRscale, int n)
{
    __shared__ float xs[BR][DIN];
    __shared__ float wmax[16][8];
    __shared__ float rowS[BR];
    const int tid = threadIdx.x;
    const int base = blockIdx.x * BR;
    for (int idx = tid; idx < BR * DIN; idx += 1024) {
        int r = idx >> 7, c = idx & 127;
        int node = base + r;
        xs[r][c] = (node < n) ? x[(size_t)node * DIN + c] : 0.f;
    }
    __syncthreads();
    const int rq = tid >> 8, ct = tid & 255;
    const int wid = tid >> 6, lane = tid & 63;
    const int j0 = ct; const bool has1 = ct < (DD - 256); const int j1 = ct + 256;
    float acc[8][2] = {};
    for (int k = 0; k < DIN; ++k) {
        const float* wr = W + (size_t)k * DD;
        float w0 = wr[j0], w1 = has1 ? wr[j1] : 0.f;
#pragma unroll
        for (int i = 0; i < 8; ++i) {
            float a = xs[rq * 8 + i][k];
            acc[i][0] = fmaf(a, w0, acc[i][0]);
            acc[i][1] = fmaf(a, w1, acc[i][1]);
        }
    }
    float bb0 = b[j0], bb1 = has1 ? b[j1] : 0.f;
    float v0[8], v1[8], lm[8];
#pragma unroll
    for (int i = 0; i < 8; ++i) {
        v0[i] = acc[i][0] + bb0;
        v1[i] = has1 ? (acc[i][1] + bb1) : 0.f;
        lm[i] = fmaxf(fabsf(v0[i]), fabsf(v1[i]));
    }
#pragma unroll
    for (int o = 32; o > 0; o >>= 1)
#pragma unroll
        for (int i = 0; i < 8; ++i) lm[i] = fmaxf(lm[i], __shfl_xor(lm[i], o));
    if (lane == 0)
#pragma unroll
        for (int i = 0; i < 8; ++i) wmax[wid][i] = lm[i];
    __syncthreads();
    if (ct < 8) {
        int r = rq * 8 + ct;
        float m = fmaxf(fmaxf(wmax[4 * rq][ct], wmax[4 * rq + 1][ct]),
                        fmaxf(wmax[4 * rq + 2][ct], wmax[4 * rq + 3][ct]));
        float S = fmaxf(m, 1e-30f) / 32767.f;
        rowS[r] = S;
        if (base + r < n) NRscale[base + r] = S;
    }
    __syncthreads();
#pragma unroll
    for (int i = 0; i < 8; ++i) {
        int r = rq * 8 + i;
        int node = base + r;
        if (node >= n) continue;
        float S = rowS[r];
        size_t idx = (size_t)node * DD + j0;
        st24(Ahi, Alo, idx, v0[i]);
        NRm[idx] = (short)rintf(v0[i] / S);
        if (has1) {
            st24(Ahi, Alo, idx + 256, v1[i]);
            NRm[idx + 256] = (short)rintf(v1[i] / S);
        }
    }
}

// ---------------- fused GIN layer: gather-agg + MFMA MLP (BRM=32) ------------
// staging: agg = (1+eps)*P[node] + sum_nbr P[nbr] -> split-bf16 LDS A-tile.
// epilogue: Q = h + vn_next[batch] (hl plane); NR max-updates with h.
__global__ __launch_bounds__(512)
void gin_kernel(const u16* __restrict__ Phi, const u8* __restrict__ Plo,
                u16* __restrict__ Qhi, u8* __restrict__ Qlo,
                short* __restrict__ NRm, float* __restrict__ NRscale,
                const int* __restrict__ row_ptr, const int* __restrict__ col_idx,
                const float* __restrict__ eps, int l,
                const short* __restrict__ W1f, const float* __restrict__ b1,
                const float* __restrict__ s1, const float* __restrict__ sb1,
                const short* __restrict__ W2f, const float* __restrict__ b2,
                const float* __restrict__ s2, const float* __restrict__ sb2,
                int relu2, const float* __restrict__ vnp,
                const int* __restrict__ batch, int writeQ, int n)
{
    __shared__ char uni[78848];
    __shared__ float rowM[32], rowSo[32], rowSn[32];
    short* agh = (short*)uni;               // [32][328]
    short* agl = (short*)(uni + 20992);     // [32][328]
    short* tlh = (short*)uni;               // [32][616]
    short* tll = (short*)(uni + 39424);     // [32][616]
    float* outb = (float*)uni;              // [32][304]

    const int tid = threadIdx.x;
    const int base = blockIdx.x * BRM;
    const int wv = tid >> 6, lane = tid & 63;
    const int cl = lane & 15, kq = lane >> 4, r0 = kq * 4;

    // staging: wave wv computes agg for rows wv*4 .. wv*4+3 (gather from P)
    {
        const float ep = 1.0f + eps[l];
        const bool two = (lane < 11);           // quads 64..74 -> cols 256..299
        const bool zpad = (lane >= 11 && lane < 16);  // quads 75..79 -> cols 300..316 (zeros)
#pragma unroll
        for (int rr = 0; rr < 4; ++rr) {
            int r = wv * 4 + rr;
            int node = base + r;
            float o0[4] = {0.f, 0.f, 0.f, 0.f}, o1[4] = {0.f, 0.f, 0.f, 0.f};
            if (node < n) {
                int e0 = row_ptr[node], e1 = row_ptr[node + 1];
                for (int e = e0; e < e1; ++e) {
                    int src = col_idx[e];
                    size_t rb = (size_t)src * DD;
                    float v[4];
                    ld24x4(Phi, Plo, rb + lane * 4, v);
                    o0[0] += v[0]; o0[1] += v[1]; o0[2] += v[2]; o0[3] += v[3];
                    if (two) {
                        ld24x4(Phi, Plo, rb + 256 + lane * 4, v);
                        o1[0] += v[0]; o1[1] += v[1]; o1[2] += v[2]; o1[3] += v[3];
                    }
                }
                float v[4];
                ld24x4(Phi, Plo, (size_t)node * DD + lane * 4, v);
#pragma unroll
                for (int q = 0; q < 4; ++q) o0[q] = fmaf(ep, v[q], o0[q]);
                if (two) {
                    ld24x4(Phi, Plo, (size_t)node * DD + 256 + lane * 4, v);
#pragma unroll
                    for (int q = 0; q < 4; ++q) o1[q] = fmaf(ep, v[q], o1[q]);
                }
            }
            // store quad `lane` (cols 4*lane)
            {
                short4v hh, ll;
#pragma unroll
                for (int q = 0; q < 4; ++q) {
                    u16 h = f2bf(o0[q]);
                    hh[q] = (short)h;
                    ll[q] = (short)f2bf(o0[q] - bf2f(h));
                }
                *(short4v*)&agh[r * 328 + lane * 4] = hh;
                *(short4v*)&agl[r * 328 + lane * 4] = ll;
            }
            // store quad 64+lane (cols 256+4*lane): computed for lanes<11, zeros for 11..15
            if (two || zpad) {
                short4v hh, ll;
#pragma unroll
                for (int q = 0; q < 4; ++q) {
                    float val = two ? o1[q] : 0.f;
                    u16 h = f2bf(val);
                    hh[q] = (short)h;
                    ll[q] = (short)f2bf(val - bf2f(h));
                }
                *(short4v*)&agh[r * 328 + 256 + lane * 4] = hh;
                *(short4v*)&agl[r * 328 + 256 + lane * 4] = ll;
            }
        }
    }
    __syncthreads();

    // phase 2: t = relu(bn1(ag @ W1))  [32 x 600]
    {
        f32x4 acc[2][5];
#pragma unroll
        for (int s = 0; s < 2; ++s)
#pragma unroll
            for (int i = 0; i < 5; ++i) acc[s][i] = (f32x4){0.f, 0.f, 0.f, 0.f};
        const bool act5 = (wv + 32) < NT2;
        for (int ks = 0; ks < NK2; ++ks) {
            short8 bh[5], bl[5];
#pragma unroll
            for (int i = 0; i < 5; ++i) {
                int t = wv + 8 * i;
                if (i < 4 || act5) {
                    const short* bp = W1f + (((size_t)t * NK2 + ks) << 10) + lane * 8;
                    bh[i] = *(const short8*)bp;
                    bl[i] = *(const short8*)(bp + 512);
                }
            }
            short8 ah0 = *(const short8*)&agh[cl * 328 + kq * 8 + ks * 32];
            short8 al0 = *(const short8*)&agl[cl * 328 + kq * 8 + ks * 32];
            short8 ah1 = *(const short8*)&agh[(16 + cl) * 328 + kq * 8 + ks * 32];
            short8 al1 = *(const short8*)&agl[(16 + cl) * 328 + kq * 8 + ks * 32];
#pragma unroll
            for (int i = 0; i < 5; ++i)
                if (i < 4 || act5) {
                    acc[0][i] = __builtin_amdgcn_mfma_f32_16x16x32_bf16(ah0, bh[i], acc[0][i], 0, 0, 0);
                    acc[1][i] = __builtin_amdgcn_mfma_f32_16x16x32_bf16(ah1, bh[i], acc[1][i], 0, 0, 0);
                }
#pragma unroll
            for (int i = 0; i < 5; ++i)
                if (i < 4 || act5) {
                    acc[0][i] = __builtin_amdgcn_mfma_f32_16x16x32_bf16(ah0, bl[i], acc[0][i], 0, 0, 0);
                    acc[1][i] = __builtin_amdgcn_mfma_f32_16x16x32_bf16(ah1, bl[i], acc[1][i], 0, 0, 0);
                }
#pragma unroll
            for (int i = 0; i < 5; ++i)
                if (i < 4 || act5) {
                    acc[0][i] = __builtin_amdgcn_mfma_f32_16x16x32_bf16(al0, bh[i], acc[0][i], 0, 0, 0);
                    acc[1][i] = __builtin_amdgcn_mfma_f32_16x16x32_bf16(al1, bh[i], acc[1][i], 0, 0, 0);
                }
        }
        __syncthreads();   // agbuf fully read; safe to overwrite as tlbuf
        if (tid < 256) {
            int r = tid >> 3, c = 600 + (tid & 7);
            tlh[r * 616 + c] = 0; tll[r * 616 + c] = 0;
        }
#pragma unroll
        for (int s = 0; s < 2; ++s)
#pragma unroll
            for (int i = 0; i < 5; ++i) {
                int t = wv + 8 * i;
                if (t >= NT2) continue;
                int cg = t * 16 + cl;
                if (cg < DD2) {
                    float bb = b1[cg], ss = s1[cg], cc = sb1[cg];
#pragma unroll
                    for (int r = 0; r < 4; ++r) {
                        float xv = fmaxf(fmaf(acc[s][i][r] + bb, ss, cc), 0.f);
                        u16 h = f2bf(xv);
                        tlh[(s * 16 + r0 + r) * 616 + cg] = (short)h;
                        tll[(s * 16 + r0 + r) * 616 + cg] = (short)f2bf(xv - bf2f(h));
                    }
                }
            }
    }
    __syncthreads();

    // phase 3: out_raw = t @ W2  [32 x 300], K=608 (19 steps)
    {
        f32x4 acc[2][3];
#pragma unroll
        for (int s = 0; s < 2; ++s)
#pragma unroll
            for (int i = 0; i < 3; ++i) acc[s][i] = (f32x4){0.f, 0.f, 0.f, 0.f};
        const bool act3 = (wv + 16) < NT3;
        for (int ks = 0; ks < NK3; ++ks) {
            short8 bh[3], bl[3];
#pragma unroll
            for (int i = 0; i < 3; ++i) {
                int t = wv + 8 * i;
                if (i < 2 || act3) {
                    const short* bp = W2f + (((size_t)t * NK3 + ks) << 10) + lane * 8;
                    bh[i] = *(const short8*)bp;
                    bl[i] = *(const short8*)(bp + 512);
                }
            }
            short8 ah0 = *(const short8*)&tlh[cl * 616 + kq * 8 + ks * 32];
            short8 al0 = *(const short8*)&tll[cl * 616 + kq * 8 + ks * 32];
            short8 ah1 = *(const short8*)&tlh[(16 + cl) * 616 + kq * 8 + ks * 32];
            short8 al1 = *(const short8*)&tll[(16 + cl) * 616 + kq * 8 + ks * 32];
#pragma unroll
            for (int i = 0; i < 3; ++i)
                if (i < 2 || act3) {
                    acc[0][i] = __builtin_amdgcn_mfma_f32_16x16x32_bf16(ah0, bh[i], acc[0][i], 0, 0, 0);
                    acc[1][i] = __builtin_amdgcn_mfma_f32_16x16x32_bf16(ah1, bh[i], acc[1][i], 0, 0, 0);
                }
#pragma unroll
            for (int i = 0; i < 3; ++i)
                if (i < 2 || act3) {
                    acc[0][i] = __builtin_amdgcn_mfma_f32_16x16x32_bf16(ah0, bl[i], acc[0][i], 0, 0, 0);
                    acc[1][i] = __builtin_amdgcn_mfma_f32_16x16x32_bf16(ah1, bl[i], acc[1][i], 0, 0, 0);
                }
#pragma unroll
            for (int i = 0; i < 3; ++i)
                if (i < 2 || act3) {
                    acc[0][i] = __builtin_amdgcn_mfma_f32_16x16x32_bf16(al0, bh[i], acc[0][i], 0, 0, 0);
                    acc[1][i] = __builtin_amdgcn_mfma_f32_16x16x32_bf16(al1, bh[i], acc[1][i], 0, 0, 0);
                }
        }
        __syncthreads();   // tlbuf fully read; safe to overwrite as outb
#pragma unroll
        for (int s = 0; s < 2; ++s)
#pragma unroll
            for (int i = 0; i < 3; ++i) {
                int t = wv + 8 * i;
                if (t >= NT3) continue;
                int cg = t * 16 + cl;
#pragma unroll
                for (int r = 0; r < 4; ++r) outb[(s * 16 + r0 + r) * 304 + cg] = acc[s][i][r];
            }
    }
    __syncthreads();

    // epilogue (a): bn2 (+relu) in place + row max
    {
        const int rr = tid >> 4;
        const int qq = tid & 15;
        float lm = 0.f;
        for (int c = qq; c < DD; c += 16) {
            float v = fmaf(outb[rr * 304 + c] + b2[c], s2[c], sb2[c]);
            if (relu2) v = fmaxf(v, 0.f);
            outb[rr * 304 + c] = v;
            lm = fmaxf(lm, fabsf(v));
        }
#pragma unroll
        for (int o = 8; o > 0; o >>= 1) lm = fmaxf(lm, __shfl_xor(lm, o));
        if (qq == 0) rowM[rr] = lm;
    }
    __syncthreads();
    // epilogue (b): per-row scale update
    if (tid < 32) {
        int node = base + tid;
        float oS = (node < n) ? NRscale[node] : 0.f;
        float newM = fmaxf(rowM[tid], oS * 32767.f);
        float nS = fmaxf(newM, 1e-30f) / 32767.f;
        rowSo[tid] = oS; rowSn[tid] = nS;
        if (node < n) NRscale[node] = nS;
    }
    __syncthreads();
    // epilogue (c): vectorized store, 4-col quads (75 quads cover 300 cols)
    for (int idx = tid; idx < 32 * 75; idx += 512) {
        int r = idx / 75, c = (idx - r * 75) * 4;
        int node = base + r;
        if (node >= n) continue;
        float oS = rowSo[r], inv = 1.0f / rowSn[r];
        size_t gidx = (size_t)node * DD + c;
        float h0 = outb[r * 304 + c + 0];
        float h1 = outb[r * 304 + c + 1];
        float h2 = outb[r * 304 + c + 2];
        float h3 = outb[r * 304 + c + 3];
        if (writeQ) {
            float hl[4];
            if (vnp) {
                const float* vrow = vnp + (size_t)batch[node] * DD;
                float4 vv = *(const float4*)(vrow + c);
                hl[0] = h0 + vv.x; hl[1] = h1 + vv.y; hl[2] = h2 + vv.z; hl[3] = h3 + vv.w;
            } else {
                hl[0] = h0; hl[1] = h1; hl[2] = h2; hl[3] = h3;
            }
            st24x4(Qhi, Qlo, gidx, hl);
        }
        short4v old = *(const short4v*)&NRm[gidx];
        short4v nw;
        nw[0] = (short)rintf(fmaxf((float)old[0] * oS, h0) * inv);
        nw[1] = (short)rintf(fmaxf((float)old[1] * oS, h1) * inv);
        nw[2] = (short)rintf(fmaxf((float)old[2] * oS, h2) * inv);
        nw[3] = (short)rintf(fmaxf((float)old[3] * oS, h3) * inv);
        *(short4v*)&NRm[gidx] = nw;
    }
}

// ---------------- gate: MFMA phase-1 GEMM (BRM=32, LDS-aliased) + dot --------
__global__ __launch_bounds__(512)
void gate_kernel(const short* __restrict__ NRm, const float* __restrict__ NRscale,
                 const short* __restrict__ W1f, const float* __restrict__ b1,
                 const float* __restrict__ s1, const float* __restrict__ sb1,
                 const float* __restrict__ W2, const float* __restrict__ b2,
                 float* __restrict__ gate, int n)
{
    __shared__ char uni[78336];
    __shared__ float sc[32];
    short* nbh = (short*)uni;
    short* nbl = (short*)(uni + 20992);
    float* tlf = (float*)uni;   // [32][612]

    const int tid = threadIdx.x;
    const int base = blockIdx.x * BRM;
    const int wv = tid >> 6, lane = tid & 63;
    const int cl = lane & 15, kq = lane >> 4, r0 = kq * 4;

    if (tid < 32) {
        int node = base + tid;
        sc[tid] = (node < n) ? NRscale[node] : 0.f;
    }
    __syncthreads();
    for (int idx = tid; idx < 32 * 80; idx += 512) {
        int r = idx / 80, c4 = (idx - r * 80) * 4;
        int node = base + r;
        float v[4] = {0.f, 0.f, 0.f, 0.f};
        if (c4 < DD && node < n) {
            short4v m4 = *(const short4v*)&NRm[(size_t)node * DD + c4];
            float s = sc[r];
            v[0] = (float)m4[0] * s; v[1] = (float)m4[1] * s;
            v[2] = (float)m4[2] * s; v[3] = (float)m4[3] * s;
        }
        short4v hh, ll;
#pragma unroll
        for (int q = 0; q < 4; ++q) {
            u16 h = f2bf(v[q]);
            hh[q] = (short)h;
            ll[q] = (short)f2bf(v[q] - bf2f(h));
        }
        *(short4v*)&nbh[r * 328 + c4] = hh;
        *(short4v*)&nbl[r * 328 + c4] = ll;
    }
    __syncthreads();

    {
        f32x4 acc[2][5];
#pragma unroll
        for (int s = 0; s < 2; ++s)
#pragma unroll
            for (int i = 0; i < 5; ++i) acc[s][i] = (f32x4){0.f, 0.f, 0.f, 0.f};
        const bool act5 = (wv + 32) < NT2;
        for (int ks = 0; ks < NK2; ++ks) {
            short8 bh[5], bl[5];
#pragma unroll
            for (int i = 0; i < 5; ++i) {
                int t = wv + 8 * i;
                if (i < 4 || act5) {
                    const short* bp = W1f + (((size_t)t * NK2 + ks) << 10) + lane * 8;
                    bh[i] = *(const short8*)bp;
                    bl[i] = *(const short8*)(bp + 512);
                }
            }
            short8 ah0 = *(const short8*)&nbh[cl * 328 + kq * 8 + ks * 32];
            short8 al0 = *(const short8*)&nbl[cl * 328 + kq * 8 + ks * 32];
            short8 ah1 = *(const short8*)&nbh[(16 + cl) * 328 + kq * 8 + ks * 32];
            short8 al1 = *(const short8*)&nbl[(16 + cl) * 328 + kq * 8 + ks * 32];
#pragma unroll
            for (int i = 0; i < 5; ++i)
                if (i < 4 || act5) {
                    acc[0][i] = __builtin_amdgcn_mfma_f32_16x16x32_bf16(ah0, bh[i], acc[0][i], 0, 0, 0);
                    acc[1][i] = __builtin_amdgcn_mfma_f32_16x16x32_bf16(ah1, bh[i], acc[1][i], 0, 0, 0);
                }
#pragma unroll
            for (int i = 0; i < 5; ++i)
                if (i < 4 || act5) {
                    acc[0][i] = __builtin_amdgcn_mfma_f32_16x16x32_bf16(ah0, bl[i], acc[0][i], 0, 0, 0);
                    acc[1][i] = __builtin_amdgcn_mfma_f32_16x16x32_bf16(ah1, bl[i], acc[1][i], 0, 0, 0);
                }
#pragma unroll
            for (int i = 0; i < 5; ++i)
                if (i < 4 || act5) {
                    acc[0][i] = __builtin_amdgcn_mfma_f32_16x16x32_bf16(al0, bh[i], acc[0][i], 0, 0, 0);
                    acc[1][i] = __builtin_amdgcn_mfma_f32_16x16x32_bf16(al1, bh[i], acc[1][i], 0, 0, 0);
                }
        }
        __syncthreads();   // nbuf fully read; safe to overwrite as tlf
#pragma unroll
        for (int s = 0; s < 2; ++s)
#pragma unroll
            for (int i = 0; i < 5; ++i) {
                int t = wv + 8 * i;
                if (t >= NT2) continue;
                int cg = t * 16 + cl;
                if (cg < DD2) {
                    float bb = b1[cg], ss = s1[cg], cc = sb1[cg];
#pragma unroll
                    for (int r = 0; r < 4; ++r)
                        tlf[(s * 16 + r0 + r) * 612 + cg] = fmaxf(fmaf(acc[s][i][r] + bb, ss, cc), 0.f);
                }
            }
    }
    __syncthreads();

    {
        const int wave = tid >> 6, ln = tid & 63;
#pragma unroll
        for (int rr = 0; rr < 4; ++rr) {
            int r = wave * 4 + rr;
            int node = base + r;
            float acc = 0.f;
            for (int j = ln; j < DD2; j += 64) acc = fmaf(tlf[r * 612 + j], W2[j], acc);
#pragma unroll
            for (int o = 32; o > 0; o >>= 1) acc += __shfl_down(acc, o);
            if (ln == 0 && node < n) gate[node] = acc + b2[0];
        }
    }
}

// ---------------- per-graph softmax-attention pooling -----------------------
__global__ void attn_pool_kernel(const float* __restrict__ gate,
                                 const short* __restrict__ NRm, const float* __restrict__ NRscale,
                                 const int* __restrict__ batch, float* __restrict__ rep, int n)
{
    __shared__ float red[320];
    __shared__ float bc[2];
    int g = blockIdx.x, t = threadIdx.x;
    int l0 = lower_bound_i(batch, n, g);
    int h0 = lower_bound_i(batch, n, g + 1);
    if (l0 >= h0) { if (t < DD) rep[(size_t)g * DD + t] = 0.f; return; }

    float m = -3.4e38f;
    for (int i = l0 + t; i < h0; i += 320) m = fmaxf(m, gate[i]);
    red[t] = m;
    __syncthreads();
    if (t < 64) {
        float mm = red[t];
        for (int s2 = t + 64; s2 < 320; s2 += 64) mm = fmaxf(mm, red[s2]);
#pragma unroll
        for (int o = 32; o > 0; o >>= 1) mm = fmaxf(mm, __shfl_down(mm, o));
        if (t == 0) bc[0] = mm;
    }
    __syncthreads();
    float gmax = bc[0];

    float ssum = 0.f;
    for (int i = l0 + t; i < h0; i += 320) ssum += expf(gate[i] - gmax);
    __syncthreads();
    red[t] = ssum;
    __syncthreads();
    if (t < 64) {
        float mm = red[t];
        for (int s2 = t + 64; s2 < 320; s2 += 64) mm += red[s2];
#pragma unroll
        for (int o = 32; o > 0; o >>= 1) mm += __shfl_down(mm, o);
        if (t == 0) bc[1] = mm;
    }
    __syncthreads();
    float inv = 1.0f / bc[1];

    if (t < DD) {
        float acc = 0.f;
        for (int i = l0; i < h0; ++i) {
            float w = expf(gate[i] - gmax) * inv;
            acc = fmaf(w, (float)NRm[(size_t)i * DD + t] * NRscale[i], acc);
        }
        rep[(size_t)g * DD + t] = acc;
    }
}

// ---------------- final projection ------------------------------------------
__global__ void final_kernel(const float* __restrict__ rep, const float* __restrict__ pW,
                             const float* __restrict__ pb, float* __restrict__ out)
{
    int g = blockIdx.x, lane = threadIdx.x;
    float a[NCLS] = {};
    for (int d = lane; d < DD; d += 64) {
        float r = rep[(size_t)g * DD + d];
#pragma unroll
        for (int c = 0; c < NCLS; ++c) a[c] = fmaf(r, pW[d * NCLS + c], a[c]);
    }
#pragma unroll
    for (int c = 0; c < NCLS; ++c) {
#pragma unroll
        for (int o = 32; o > 0; o >>= 1) a[c] += __shfl_down(a[c], o);
    }
    if (lane == 0) {
#pragma unroll
        for (int c = 0; c < NCLS; ++c) out[g * NCLS + c] = a[c] + pb[c];
    }
}

// ---------------------------------------------------------------------------
extern "C" void kernel_launch(void* const* d_in, const int* in_sizes, int n_in,
                              void* d_out, int out_size, void* d_ws, size_t ws_size,
                              hipStream_t stream)
{
    (void)n_in;
    const float* x      = (const float*)d_in[0];
    const int*   ei     = (const int*)d_in[1];
    const int*   braw   = (const int*)d_in[2];
    const float* enc_W  = (const float*)d_in[3];
    const float* enc_b  = (const float*)d_in[4];
    const float* eps    = (const float*)d_in[5];
    const float* cW1    = (const float*)d_in[6];
    const float* cb1    = (const float*)d_in[7];
    const float* cbn_s  = (const float*)d_in[8];
    const float* cbn_b  = (const float*)d_in[9];
    const float* cW2    = (const float*)d_in[10];
    const float* cb2    = (const float*)d_in[11];
    const float* bn_s   = (const float*)d_in[12];
    const float* bn_b   = (const float*)d_in[13];
    const float* vn0    = (const float*)d_in[14];
    const float* vW1    = (const float*)d_in[15];
    const float* vb1    = (const float*)d_in[16];
    const float* vbn1_s = (const float*)d_in[17];
    const float* vbn1_b = (const float*)d_in[18];
    const float* vW2    = (const float*)d_in[19];
    const float* vb2    = (const float*)d_in[20];
    const float* vbn2_s = (const float*)d_in[21];
    const float* vbn2_b = (const float*)d_in[22];
    const float* gW1    = (const float*)d_in[23];
    const float* gb1    = (const float*)d_in[24];
    const float* gbn_s  = (const float*)d_in[25];
    const float* gbn_b  = (const float*)d_in[26];
    const float* gW2    = (const float*)d_in[27];
    const float* gb2    = (const float*)d_in[28];
    const float* pW     = (const float*)d_in[29];
    const float* pb     = (const float*)d_in[30];
    float* out = (float*)d_out;

    const int N = in_sizes[0] / DIN;
    const int E = NEDGES;
    int fe = in_sizes[1] / (2 * E);
    if (fe < 1) fe = 1; if (fe > 2) fe = 2;

    // ---- workspace carve ----
    char* wsp = (char*)d_ws;
    size_t off = 0;
    auto carve = [&](size_t nbytes) -> void* {
        void* p = (void*)(wsp + off);
        off += ((nbytes + 255) / 256) * 256;
        return p;
    };
    u16*   Ahi     = (u16*)  carve((size_t)N * DD * 2);
    u8*    Alo     = (u8*)   carve((size_t)N * DD);
    u16*   Bhi     = (u16*)  carve((size_t)N * DD * 2);
    u8*    Blo     = (u8*)   carve((size_t)N * DD);
    short* NRm     = (short*)carve((size_t)N * DD * 2);
    float* NRscale = (float*)carve((size_t)N * 4);
    float* vnBuf   = (float*)carve((size_t)NGRAPH * DD * 4);
    float* vtmpBuf = (float*)carve((size_t)NGRAPH * DD * 4);
    float* repBuf  = (float*)carve((size_t)NGRAPH * DD * 4);
    float* gateBuf = (float*)carve((size_t)N * 4);
    int*   batch32 = (int*)  carve((size_t)N * 4);
    int*   row_ptr = (int*)  carve(((size_t)N + 1) * 4);
    int*   cursor  = (int*)  carve((size_t)N * 4);
    int*   col_idx = (int*)  carve((size_t)E * 4);
    short* W1f     = (short*)carve((size_t)NLAYER * W1F_SZ * 2);
    short* W2f     = (short*)carve((size_t)NLAYER * W1F_SZ * 2);
    short* gW1f    = (short*)carve((size_t)W1F_SZ * 2);

    if (off > ws_size) {
        diag_kernel<<<(out_size + 255) / 256, 256, 0, stream>>>(out, out_size, (float)ws_size);
        return;
    }

    // ---- weight packing ----
    const int pkBlocks = (NT2 * NK2 * 64 + 255) / 256;
    for (int l = 0; l < NLAYER; ++l) {
        packW_kernel<<<pkBlocks, 256, 0, stream>>>(cW1 + (size_t)l * DD * DD2, DD, DD2,
                                                   NT2, NK2, W1f + (size_t)l * W1F_SZ);
        packW_kernel<<<pkBlocks, 256, 0, stream>>>(cW2 + (size_t)l * DD2 * DD, DD2, DD,
                                                   NT3, NK3, W2f + (size_t)l * W1F_SZ);
    }
    packW_kernel<<<pkBlocks, 256, 0, stream>>>(gW1, DD, DD2, NT2, NK2, gW1f);

    bconv_kernel<<<(N + 255) / 256, 256, 0, stream>>>(braw, N, batch32);

    (void)hipMemsetAsync(cursor, 0, (size_t)N * 4, stream);
    deg_kernel<<<(E + 255) / 256, 256, 0, stream>>>(ei, fe, E, cursor);
    scan_kernel<<<1, 1024, 0, stream>>>(cursor, row_ptr, N);
    (void)hipMemcpyAsync(cursor, row_ptr, (size_t)N * 4, hipMemcpyDeviceToDevice, stream);
    scatter_kernel<<<(E + 255) / 256, 256, 0, stream>>>(ei, fe, E, cursor, col_idx);

    vn_init_kernel<<<(NGRAPH * DD + 255) / 256, 256, 0, stream>>>(vnBuf, vn0);

    const int nblk32 = (N + BR - 1) / BR;
    const int nblkM  = (N + BRM - 1) / BRM;

    encoder_kernel<<<nblk32, 1024, 0, stream>>>(x, enc_W, enc_b, Ahi, Alo, NRm, NRscale, N);

    u16 *Phi = Ahi, *Qhi = Bhi; u8 *Plo = Alo, *Qlo = Blo;
    for (int l = 0; l < NLAYER; ++l) {
        const bool hasVn = (l < NLAYER - 1);
        if (hasVn)
            vtmp_kernel<<<NGRAPH, 320, 0, stream>>>(Phi, Plo, batch32, vnBuf, vtmpBuf, N);
        if (hasVn)
            vn_mlp_kernel<<<NGRAPH, 512, 0, stream>>>(
                vtmpBuf,
                vW1 + (size_t)l * DD * DD2, vb1 + (size_t)l * DD2,
                vbn1_s + (size_t)l * DD2, vbn1_b + (size_t)l * DD2,
                vW2 + (size_t)l * DD2 * DD, vb2 + (size_t)l * DD,
                vbn2_s + (size_t)l * DD, vbn2_b + (size_t)l * DD,
                vnBuf);
        gin_kernel<<<nblkM, 512, 0, stream>>>(
            Phi, Plo, Qhi, Qlo, NRm, NRscale,
            row_ptr, col_idx, eps, l,
            W1f + (size_t)l * W1F_SZ, cb1 + (size_t)l * DD2,
            cbn_s + (size_t)l * DD2, cbn_b + (size_t)l * DD2,
            W2f + (size_t)l * W1F_SZ, cb2 + (size_t)l * DD,
            bn_s + (size_t)l * DD, bn_b + (size_t)l * DD,
            hasVn ? 1 : 0,
            hasVn ? vnBuf : (const float*)nullptr, batch32,
            hasVn ? 1 : 0, N);
        u16* th = Phi; Phi = Qhi; Qhi = th;
        u8*  tb = Plo; Plo = Qlo; Qlo = tb;
    }

    gate_kernel<<<nblkM, 512, 0, stream>>>(NRm, NRscale, gW1f, gb1, gbn_s, gbn_b,
                                           gW2, gb2, gateBuf, N);
    attn_pool_kernel<<<NGRAPH, 320, 0, stream>>>(gateBuf, NRm, NRscale, batch32, repBuf, N);
    final_kernel<<<NGRAPH, 64, 0, stream>>>(repBuf, pW, pb, out);
}

// Round 20
// 3913.914 us; speedup vs baseline: 1.1603x; 1.1603x over previous
//
#include <hip/hip_runtime.h>
#include <cstddef>

#define NGRAPH 1000
#define NEDGES 1600000
#define DD     300
#define DD2    600
#define DIN    128
#define NLAYER 5
#define NCLS   10
#define BR     32
#define BRM    32

// MFMA fragment geometry
#define NT2 38
#define NK2 10
#define NT3 19
#define NK3 19
#define WFRAG 1024
#define W1F_SZ (NT2*NK2*WFRAG)

typedef unsigned short u16;
typedef unsigned char  u8;
typedef unsigned int   u32;
typedef __attribute__((ext_vector_type(8))) short short8;
typedef __attribute__((ext_vector_type(4))) short short4v;
typedef __attribute__((ext_vector_type(4))) float f32x4;

// ---------------- bf16 helpers ----------------------------------------------
__device__ __forceinline__ u16 f2bf(float f) {
    u32 u; __builtin_memcpy(&u, &f, 4);
    u = (u + 0x7FFFu + ((u >> 16) & 1u)) >> 16;
    return (u16)u;
}
__device__ __forceinline__ float bf2f(u16 h) {
    u32 u = ((u32)h) << 16;
    float f; __builtin_memcpy(&f, &u, 4); return f;
}

// ---------------- fp24 storage helpers (hi u16 plane + lo u8 plane) --------
__device__ __forceinline__ float ld24(const u16* __restrict__ hi, const u8* __restrict__ lo,
                                      size_t idx) {
    u32 u = ((u32)hi[idx] << 16) | ((u32)lo[idx] << 8);
    float f; __builtin_memcpy(&f, &u, 4); return f;
}
__device__ __forceinline__ void st24(u16* __restrict__ hi, u8* __restrict__ lo,
                                     size_t idx, float f) {
    u32 u; __builtin_memcpy(&u, &f, 4);
    u32 r = u + 0x7Fu + ((u >> 8) & 1u);
    hi[idx] = (u16)(r >> 16); lo[idx] = (u8)(r >> 8);
}
__device__ __forceinline__ void ld24x4(const u16* __restrict__ hi, const u8* __restrict__ lo,
                                       size_t idx, float o[4]) {
    ushort4 h = *(const ushort4*)(hi + idx);
    uchar4  l = *(const uchar4*)(lo + idx);
    u32 u0 = ((u32)h.x << 16) | ((u32)l.x << 8);
    u32 u1 = ((u32)h.y << 16) | ((u32)l.y << 8);
    u32 u2 = ((u32)h.z << 16) | ((u32)l.z << 8);
    u32 u3 = ((u32)h.w << 16) | ((u32)l.w << 8);
    __builtin_memcpy(&o[0], &u0, 4); __builtin_memcpy(&o[1], &u1, 4);
    __builtin_memcpy(&o[2], &u2, 4); __builtin_memcpy(&o[3], &u3, 4);
}
__device__ __forceinline__ void st24x4(u16* __restrict__ hi, u8* __restrict__ lo,
                                       size_t idx, const float v[4]) {
    u32 u[4];
#pragma unroll
    for (int q = 0; q < 4; ++q) {
        u32 t; __builtin_memcpy(&t, &v[q], 4);
        u[q] = t + 0x7Fu + ((t >> 8) & 1u);
    }
    ushort4 h; h.x = (u16)(u[0] >> 16); h.y = (u16)(u[1] >> 16);
    h.z = (u16)(u[2] >> 16); h.w = (u16)(u[3] >> 16);
    uchar4 l8; l8.x = (u8)(u[0] >> 8); l8.y = (u8)(u[1] >> 8);
    l8.z = (u8)(u[2] >> 8); l8.w = (u8)(u[3] >> 8);
    *(ushort4*)(hi + idx) = h;
    *(uchar4*)(lo + idx) = l8;
}

// ---------------------------------------------------------------------------
__global__ void diag_kernel(float* __restrict__ out, int n, float val)
{
    int i = blockIdx.x * 256 + threadIdx.x;
    if (i < n) out[i] = val;
}

__global__ void vn_init_kernel(float* __restrict__ vn, const float* __restrict__ vn0)
{
    int idx = blockIdx.x * 256 + threadIdx.x;
    if (idx < NGRAPH * DD) vn[idx] = vn0[idx % DD];
}

__global__ void bconv_kernel(const int* __restrict__ braw, int n, int* __restrict__ b32)
{
    int i = blockIdx.x * 256 + threadIdx.x;
    if (i >= n) return;
    int fs = (braw[n - 1] == 0) ? 2 : 1;
    b32[i] = braw[(size_t)i * fs];
}

// pack W [K x N] fp32 -> MFMA B-fragments, split bf16 hi/lo.
__global__ void packW_kernel(const float* __restrict__ W, int K, int N,
                             int nT, int nK, short* __restrict__ dst)
{
    int idx = blockIdx.x * 256 + threadIdx.x;
    int total = nT * nK * 64;
    if (idx >= total) return;
    int lane = idx & 63;
    int tk = idx >> 6;
    int nn = (tk / nK) * 16 + (lane & 15);
    int k0 = (tk % nK) * 32 + (lane >> 4) * 8;
    short* o = dst + ((size_t)tk << 10) + lane * 8;
#pragma unroll
    for (int j = 0; j < 8; ++j) {
        float v = (nn < N && (k0 + j) < K) ? W[(size_t)(k0 + j) * N + nn] : 0.f;
        u16 h = f2bf(v);
        o[j] = (short)h;
        o[512 + j] = (short)f2bf(v - bf2f(h));
    }
}

// ---------------- CSR build -------------------------------------------------
__global__ void deg_kernel(const int* __restrict__ ei, int fe, int E, int* __restrict__ deg)
{
    int e = blockIdx.x * 256 + threadIdx.x;
    if (e < E) atomicAdd(&deg[ei[(size_t)fe * (E + e)]], 1);
}

__global__ void scan_kernel(const int* __restrict__ deg, int* __restrict__ row_ptr, int n)
{
    __shared__ int sd[1024];
    int t = threadIdx.x;
    int C = (n + 1023) >> 10;
    int i0 = t * C, i1 = i0 + C; if (i1 > n) i1 = n; if (i0 > n) i0 = n;
    int s = 0;
    for (int i = i0; i < i1; ++i) s += deg[i];
    sd[t] = s;
    __syncthreads();
    for (int o = 1; o < 1024; o <<= 1) {
        int x = (t >= o) ? sd[t - o] : 0;
        __syncthreads();
        sd[t] += x;
        __syncthreads();
    }
    int run = (t == 0) ? 0 : sd[t - 1];
    for (int i = i0; i < i1; ++i) { row_ptr[i] = run; run += deg[i]; }
    if (t == 1023) row_ptr[n] = sd[1023];
}

__global__ void scatter_kernel(const int* __restrict__ ei, int fe, int E,
                               int* __restrict__ cursor, int* __restrict__ col_idx)
{
    int e = blockIdx.x * 256 + threadIdx.x;
    if (e < E) {
        int d = ei[(size_t)fe * (E + e)];
        int s = ei[(size_t)fe * e];
        int p = atomicAdd(&cursor[d], 1);
        col_idx[p] = s;
    }
}

__device__ __forceinline__ int lower_bound_i(const int* __restrict__ arr, int n, int key)
{
    int lo = 0, hi = n;
    while (lo < hi) {
        int mid = (lo + hi) >> 1;
        if (arr[mid] < key) lo = mid + 1; else hi = mid;
    }
    return lo;
}

// ---------------- vtmp[g] = segment_sum(hl) + vn  (row-unrolled x4) ----------
__global__ void vtmp_kernel(const u16* __restrict__ hi, const u8* __restrict__ lo,
                            const int* __restrict__ batch, const float* __restrict__ vn,
                            float* __restrict__ vtmp, int n)
{
    int g = blockIdx.x, t = threadIdx.x;
    int l0 = lower_bound_i(batch, n, g);
    int h0 = lower_bound_i(batch, n, g + 1);
    if (t >= DD) return;
    float a0 = 0.f, a1 = 0.f, a2 = 0.f, a3 = 0.f;
    int i = l0;
    for (; i + 3 < h0; i += 4) {
        a0 += ld24(hi, lo, (size_t)(i + 0) * DD + t);
        a1 += ld24(hi, lo, (size_t)(i + 1) * DD + t);
        a2 += ld24(hi, lo, (size_t)(i + 2) * DD + t);
        a3 += ld24(hi, lo, (size_t)(i + 3) * DD + t);
    }
    for (; i < h0; ++i) a0 += ld24(hi, lo, (size_t)i * DD + t);
    vtmp[(size_t)g * DD + t] = ((a0 + a1) + (a2 + a3)) + vn[(size_t)g * DD + t];
}

// ---------------- fused vn MLP ----------------------------------------------
__global__ void vn_mlp_kernel(const float* __restrict__ vtmp,
                              const float* __restrict__ W1, const float* __restrict__ b1,
                              const float* __restrict__ s1, const float* __restrict__ sb1,
                              const float* __restrict__ W2, const float* __restrict__ b2,
                              const float* __restrict__ s2, const float* __restrict__ sb2,
                              float* __restrict__ vn)
{
    __shared__ float vt[DD];
    __shared__ float us[DD2];
    int g = blockIdx.x, t = threadIdx.x;
    if (t < DD) vt[t] = vtmp[(size_t)g * DD + t];
    __syncthreads();
    for (int j = t; j < DD2; j += 512) {
        float acc = 0.f;
        for (int k = 0; k < DD; ++k) acc = fmaf(vt[k], W1[(size_t)k * DD2 + j], acc);
        us[j] = fmaxf(fmaf(acc + b1[j], s1[j], sb1[j]), 0.f);
    }
    __syncthreads();
    for (int j = t; j < DD; j += 512) {
        float acc = 0.f;
        for (int k = 0; k < DD2; ++k) acc = fmaf(us[k], W2[(size_t)k * DD + j], acc);
        vn[(size_t)g * DD + j] = fmaxf(fmaf(acc + b2[j], s2[j], sb2[j]), 0.f);
    }
}

// ---------------- encoder (writes h0 = hl0 since vn0 = 0) --------------------
__global__ __launch_bounds__(1024)
void encoder_kernel(const float* __restrict__ x, const float* __restrict__ W,
                    const float* __restrict__ b,
                    u16* __restrict__ Ahi, u8* __restrict__ Alo,
                    short* __restrict__ NRm, float* __restrict__ NRscale, int n)
{
    __shared__ float xs[BR][DIN];
    __shared__ float wmax[16][8];
    __shared__ float rowS[BR];
    const int tid = threadIdx.x;
    const int base = blockIdx.x * BR;
    for (int idx = tid; idx < BR * DIN; idx += 1024) {
        int r = idx >> 7, c = idx & 127;
        int node = base + r;
        xs[r][c] = (node < n) ? x[(size_t)node * DIN + c] : 0.f;
    }
    __syncthreads();
    const int rq = tid >> 8, ct = tid & 255;
    const int wid = tid >> 6, lane = tid & 63;
    const int j0 = ct; const bool has1 = ct < (DD - 256); const int j1 = ct + 256;
    float acc[8][2] = {};
    for (int k = 0; k < DIN; ++k) {
        const float* wr = W + (size_t)k * DD;
        float w0 = wr[j0], w1 = has1 ? wr[j1] : 0.f;
#pragma unroll
        for (int i = 0; i < 8; ++i) {
            float a = xs[rq * 8 + i][k];
            acc[i][0] = fmaf(a, w0, acc[i][0]);
            acc[i][1] = fmaf(a, w1, acc[i][1]);
        }
    }
    float bb0 = b[j0], bb1 = has1 ? b[j1] : 0.f;
    float v0[8], v1[8], lm[8];
#pragma unroll
    for (int i = 0; i < 8; ++i) {
        v0[i] = acc[i][0] + bb0;
        v1[i] = has1 ? (acc[i][1] + bb1) : 0.f;
        lm[i] = fmaxf(fabsf(v0[i]), fabsf(v1[i]));
    }
#pragma unroll
    for (int o = 32; o > 0; o >>= 1)
#pragma unroll
        for (int i = 0; i < 8; ++i) lm[i] = fmaxf(lm[i], __shfl_xor(lm[i], o));
    if (lane == 0)
#pragma unroll
        for (int i = 0; i < 8; ++i) wmax[wid][i] = lm[i];
    __syncthreads();
    if (ct < 8) {
        int r = rq * 8 + ct;
        float m = fmaxf(fmaxf(wmax[4 * rq][ct], wmax[4 * rq + 1][ct]),
                        fmaxf(wmax[4 * rq + 2][ct], wmax[4 * rq + 3][ct]));
        float S = fmaxf(m, 1e-30f) / 32767.f;
        rowS[r] = S;
        if (base + r < n) NRscale[base + r] = S;
    }
    __syncthreads();
#pragma unroll
    for (int i = 0; i < 8; ++i) {
        int r = rq * 8 + i;
        int node = base + r;
        if (node >= n) continue;
        float S = rowS[r];
        size_t idx = (size_t)node * DD + j0;
        st24(Ahi, Alo, idx, v0[i]);
        NRm[idx] = (short)rintf(v0[i] / S);
        if (has1) {
            st24(Ahi, Alo, idx + 256, v1[i]);
            NRm[idx + 256] = (short)rintf(v1[i] / S);
        }
    }
}

// ---------------- aggregate (edge loop unrolled x2) ---------------------------
__global__ __launch_bounds__(256)
void agg_kernel(const u16* __restrict__ Phi, const u8* __restrict__ Plo,
                u16* __restrict__ Qhi, u8* __restrict__ Qlo,
                const int* __restrict__ row_ptr, const int* __restrict__ col_idx,
                const float* __restrict__ eps, int l, int n)
{
    int node = blockIdx.x * 4 + (threadIdx.x >> 6);
    int lane = threadIdx.x & 63;
    if (node >= n) return;
    const float ep = 1.0f + eps[l];
    const bool two = (lane < 11);
    float a0[4] = {0.f, 0.f, 0.f, 0.f}, a1[4] = {0.f, 0.f, 0.f, 0.f};
    float b0[4] = {0.f, 0.f, 0.f, 0.f}, b1[4] = {0.f, 0.f, 0.f, 0.f};
    int e0 = row_ptr[node], e1 = row_ptr[node + 1];
    int e = e0;
    for (; e + 1 < e1; e += 2) {
        int s0 = col_idx[e], s1 = col_idx[e + 1];
        size_t rb0 = (size_t)s0 * DD, rb1 = (size_t)s1 * DD;
        float v[4], w[4];
        ld24x4(Phi, Plo, rb0 + lane * 4, v);
        ld24x4(Phi, Plo, rb1 + lane * 4, w);
        a0[0] += v[0]; a0[1] += v[1]; a0[2] += v[2]; a0[3] += v[3];
        b0[0] += w[0]; b0[1] += w[1]; b0[2] += w[2]; b0[3] += w[3];
        if (two) {
            ld24x4(Phi, Plo, rb0 + 256 + lane * 4, v);
            ld24x4(Phi, Plo, rb1 + 256 + lane * 4, w);
            a1[0] += v[0]; a1[1] += v[1]; a1[2] += v[2]; a1[3] += v[3];
            b1[0] += w[0]; b1[1] += w[1]; b1[2] += w[2]; b1[3] += w[3];
        }
    }
    if (e < e1) {
        int s0 = col_idx[e];
        size_t rb0 = (size_t)s0 * DD;
        float v[4];
        ld24x4(Phi, Plo, rb0 + lane * 4, v);
        a0[0] += v[0]; a0[1] += v[1]; a0[2] += v[2]; a0[3] += v[3];
        if (two) {
            ld24x4(Phi, Plo, rb0 + 256 + lane * 4, v);
            a1[0] += v[0]; a1[1] += v[1]; a1[2] += v[2]; a1[3] += v[3];
        }
    }
    size_t ob = (size_t)node * DD;
    float v[4], o[4];
    ld24x4(Phi, Plo, ob + lane * 4, v);
#pragma unroll
    for (int q = 0; q < 4; ++q) o[q] = fmaf(ep, v[q], a0[q] + b0[q]);
    st24x4(Qhi, Qlo, ob + lane * 4, o);
    if (two) {
        ld24x4(Phi, Plo, ob + 256 + lane * 4, v);
#pragma unroll
        for (int q = 0; q < 4; ++q) o[q] = fmaf(ep, v[q], a1[q] + b1[q]);
        st24x4(Qhi, Qlo, ob + 256 + lane * 4, o);
    }
}

// ---------------- MLP via split-bf16 MFMA (BRM=32, LDS-aliased phases) -------
__global__ __launch_bounds__(512)
void mlp_kernel(u16* __restrict__ Qhi, u8* __restrict__ Qlo,
                short* __restrict__ NRm, float* __restrict__ NRscale,
                const short* __restrict__ W1f, const float* __restrict__ b1,
                const float* __restrict__ s1, const float* __restrict__ sb1,
                const short* __restrict__ W2f, const float* __restrict__ b2,
                const float* __restrict__ s2, const float* __restrict__ sb2,
                int relu2, const float* __restrict__ vnp,
                const int* __restrict__ batch, int writeQ, int n)
{
    __shared__ char uni[78848];
    __shared__ float rowM[32], rowSo[32], rowSn[32];
    short* agh = (short*)uni;               // [32][328]
    short* agl = (short*)(uni + 20992);     // [32][328]
    short* tlh = (short*)uni;               // [32][616]
    short* tll = (short*)(uni + 39424);     // [32][616]
    float* outb = (float*)uni;              // [32][304]

    const int tid = threadIdx.x;
    const int base = blockIdx.x * BRM;
    const int wv = tid >> 6, lane = tid & 63;
    const int cl = lane & 15, kq = lane >> 4, r0 = kq * 4;

    // stage A as split bf16 (vectorized 4-col quads; zeros beyond DD / n)
    for (int idx = tid; idx < 32 * 80; idx += 512) {
        int r = idx / 80, c4 = (idx - r * 80) * 4;
        int node = base + r;
        float v[4] = {0.f, 0.f, 0.f, 0.f};
        if (c4 < DD && node < n) ld24x4(Qhi, Qlo, (size_t)node * DD + c4, v);
        short4v hh, ll;
#pragma unroll
        for (int q = 0; q < 4; ++q) {
            u16 h = f2bf(v[q]);
            hh[q] = (short)h;
            ll[q] = (short)f2bf(v[q] - bf2f(h));
        }
        *(short4v*)&agh[r * 328 + c4] = hh;
        *(short4v*)&agl[r * 328 + c4] = ll;
    }
    __syncthreads();

    // phase 2: t = relu(bn1(ag @ W1))  [32 x 600]
    {
        f32x4 acc[2][5];
#pragma unroll
        for (int s = 0; s < 2; ++s)
#pragma unroll
            for (int i = 0; i < 5; ++i) acc[s][i] = (f32x4){0.f, 0.f, 0.f, 0.f};
        const bool act5 = (wv + 32) < NT2;
        for (int ks = 0; ks < NK2; ++ks) {
            short8 bh[5], bl[5];
#pragma unroll
            for (int i = 0; i < 5; ++i) {
                int t = wv + 8 * i;
                if (i < 4 || act5) {
                    const short* bp = W1f + (((size_t)t * NK2 + ks) << 10) + lane * 8;
                    bh[i] = *(const short8*)bp;
                    bl[i] = *(const short8*)(bp + 512);
                }
            }
            short8 ah0 = *(const short8*)&agh[cl * 328 + kq * 8 + ks * 32];
            short8 al0 = *(const short8*)&agl[cl * 328 + kq * 8 + ks * 32];
            short8 ah1 = *(const short8*)&agh[(16 + cl) * 328 + kq * 8 + ks * 32];
            short8 al1 = *(const short8*)&agl[(16 + cl) * 328 + kq * 8 + ks * 32];
#pragma unroll
            for (int i = 0; i < 5; ++i)
                if (i < 4 || act5) {
                    acc[0][i] = __builtin_amdgcn_mfma_f32_16x16x32_bf16(ah0, bh[i], acc[0][i], 0, 0, 0);
                    acc[1][i] = __builtin_amdgcn_mfma_f32_16x16x32_bf16(ah1, bh[i], acc[1][i], 0, 0, 0);
                }
#pragma unroll
            for (int i = 0; i < 5; ++i)
                if (i < 4 || act5) {
                    acc[0][i] = __builtin_amdgcn_mfma_f32_16x16x32_bf16(ah0, bl[i], acc[0][i], 0, 0, 0);
                    acc[1][i] = __builtin_amdgcn_mfma_f32_16x16x32_bf16(ah1, bl[i], acc[1][i], 0, 0, 0);
                }
#pragma unroll
            for (int i = 0; i < 5; ++i)
                if (i < 4 || act5) {
                    acc[0][i] = __builtin_amdgcn_mfma_f32_16x16x32_bf16(al0, bh[i], acc[0][i], 0, 0, 0);
                    acc[1][i] = __builtin_amdgcn_mfma_f32_16x16x32_bf16(al1, bh[i], acc[1][i], 0, 0, 0);
                }
        }
        __syncthreads();   // agbuf fully read; safe to overwrite as tlbuf
        if (tid < 256) {
            int r = tid >> 3, c = 600 + (tid & 7);
            tlh[r * 616 + c] = 0; tll[r * 616 + c] = 0;
        }
#pragma unroll
        for (int s = 0; s < 2; ++s)
#pragma unroll
            for (int i = 0; i < 5; ++i) {
                int t = wv + 8 * i;
                if (t >= NT2) continue;
                int cg = t * 16 + cl;
                if (cg < DD2) {
                    float bb = b1[cg], ss = s1[cg], cc = sb1[cg];
#pragma unroll
                    for (int r = 0; r < 4; ++r) {
                        float xv = fmaxf(fmaf(acc[s][i][r] + bb, ss, cc), 0.f);
                        u16 h = f2bf(xv);
                        tlh[(s * 16 + r0 + r) * 616 + cg] = (short)h;
                        tll[(s * 16 + r0 + r) * 616 + cg] = (short)f2bf(xv - bf2f(h));
                    }
                }
            }
    }
    __syncthreads();

    // phase 3: out_raw = t @ W2  [32 x 300], K=608 (19 steps)
    {
        f32x4 acc[2][3];
#pragma unroll
        for (int s = 0; s < 2; ++s)
#pragma unroll
            for (int i = 0; i < 3; ++i) acc[s][i] = (f32x4){0.f, 0.f, 0.f, 0.f};
        const bool act3 = (wv + 16) < NT3;
        for (int ks = 0; ks < NK3; ++ks) {
            short8 bh[3], bl[3];
#pragma unroll
            for (int i = 0; i < 3; ++i) {
                int t = wv + 8 * i;
                if (i < 2 || act3) {
                    const short* bp = W2f + (((size_t)t * NK3 + ks) << 10) + lane * 8;
                    bh[i] = *(const short8*)bp;
                    bl[i] = *(const short8*)(bp + 512);
                }
            }
            short8 ah0 = *(const short8*)&tlh[cl * 616 + kq * 8 + ks * 32];
            short8 al0 = *(const short8*)&tll[cl * 616 + kq * 8 + ks * 32];
            short8 ah1 = *(const short8*)&tlh[(16 + cl) * 616 + kq * 8 + ks * 32];
            short8 al1 = *(const short8*)&tll[(16 + cl) * 616 + kq * 8 + ks * 32];
#pragma unroll
            for (int i = 0; i < 3; ++i)
                if (i < 2 || act3) {
                    acc[0][i] = __builtin_amdgcn_mfma_f32_16x16x32_bf16(ah0, bh[i], acc[0][i], 0, 0, 0);
                    acc[1][i] = __builtin_amdgcn_mfma_f32_16x16x32_bf16(ah1, bh[i], acc[1][i], 0, 0, 0);
                }
#pragma unroll
            for (int i = 0; i < 3; ++i)
                if (i < 2 || act3) {
                    acc[0][i] = __builtin_amdgcn_mfma_f32_16x16x32_bf16(ah0, bl[i], acc[0][i], 0, 0, 0);
                    acc[1][i] = __builtin_amdgcn_mfma_f32_16x16x32_bf16(ah1, bl[i], acc[1][i], 0, 0, 0);
                }
#pragma unroll
            for (int i = 0; i < 3; ++i)
                if (i < 2 || act3) {
                    acc[0][i] = __builtin_amdgcn_mfma_f32_16x16x32_bf16(al0, bh[i], acc[0][i], 0, 0, 0);
                    acc[1][i] = __builtin_amdgcn_mfma_f32_16x16x32_bf16(al1, bh[i], acc[1][i], 0, 0, 0);
                }
        }
        __syncthreads();   // tlbuf fully read; safe to overwrite as outb
#pragma unroll
        for (int s = 0; s < 2; ++s)
#pragma unroll
            for (int i = 0; i < 3; ++i) {
                int t = wv + 8 * i;
                if (t >= NT3) continue;
                int cg = t * 16 + cl;
#pragma unroll
                for (int r = 0; r < 4; ++r) outb[(s * 16 + r0 + r) * 304 + cg] = acc[s][i][r];
            }
    }
    __syncthreads();

    // epilogue (a): bn2 (+relu) in place + row max
    {
        const int rr = tid >> 4;
        const int qq = tid & 15;
        float lm = 0.f;
        for (int c = qq; c < DD; c += 16) {
            float v = fmaf(outb[rr * 304 + c] + b2[c], s2[c], sb2[c]);
            if (relu2) v = fmaxf(v, 0.f);
            outb[rr * 304 + c] = v;
            lm = fmaxf(lm, fabsf(v));
        }
#pragma unroll
        for (int o = 8; o > 0; o >>= 1) lm = fmaxf(lm, __shfl_xor(lm, o));
        if (qq == 0) rowM[rr] = lm;
    }
    __syncthreads();
    // epilogue (b): per-row scale update
    if (tid < 32) {
        int node = base + tid;
        float oS = (node < n) ? NRscale[node] : 0.f;
        float newM = fmaxf(rowM[tid], oS * 32767.f);
        float nS = fmaxf(newM, 1e-30f) / 32767.f;
        rowSo[tid] = oS; rowSn[tid] = nS;
        if (node < n) NRscale[node] = nS;
    }
    __syncthreads();
    // epilogue (c): vectorized store, 4-col quads (75 quads cover 300 cols)
    for (int idx = tid; idx < 32 * 75; idx += 512) {
        int r = idx / 75, c = (idx - r * 75) * 4;
        int node = base + r;
        if (node >= n) continue;
        float oS = rowSo[r], inv = 1.0f / rowSn[r];
        size_t gidx = (size_t)node * DD + c;
        float h0 = outb[r * 304 + c + 0];
        float h1 = outb[r * 304 + c + 1];
        float h2 = outb[r * 304 + c + 2];
        float h3 = outb[r * 304 + c + 3];
        if (writeQ) {
            float hl[4];
            if (vnp) {
                const float* vrow = vnp + (size_t)batch[node] * DD;
                float4 vv = *(const float4*)(vrow + c);
                hl[0] = h0 + vv.x; hl[1] = h1 + vv.y; hl[2] = h2 + vv.z; hl[3] = h3 + vv.w;
            } else {
                hl[0] = h0; hl[1] = h1; hl[2] = h2; hl[3] = h3;
            }
            st24x4(Qhi, Qlo, gidx, hl);
        }
        short4v old = *(const short4v*)&NRm[gidx];
        short4v nw;
        nw[0] = (short)rintf(fmaxf((float)old[0] * oS, h0) * inv);
        nw[1] = (short)rintf(fmaxf((float)old[1] * oS, h1) * inv);
        nw[2] = (short)rintf(fmaxf((float)old[2] * oS, h2) * inv);
        nw[3] = (short)rintf(fmaxf((float)old[3] * oS, h3) * inv);
        *(short4v*)&NRm[gidx] = nw;
    }
}

// ---------------- gate: MFMA phase-1 GEMM (BRM=32, LDS-aliased) + dot --------
__global__ __launch_bounds__(512)
void gate_kernel(const short* __restrict__ NRm, const float* __restrict__ NRscale,
                 const short* __restrict__ W1f, const float* __restrict__ b1,
                 const float* __restrict__ s1, const float* __restrict__ sb1,
                 const float* __restrict__ W2, const float* __restrict__ b2,
                 float* __restrict__ gate, int n)
{
    __shared__ char uni[78336];
    __shared__ float sc[32];
    short* nbh = (short*)uni;
    short* nbl = (short*)(uni + 20992);
    float* tlf = (float*)uni;   // [32][612]

    const int tid = threadIdx.x;
    const int base = blockIdx.x * BRM;
    const int wv = tid >> 6, lane = tid & 63;
    const int cl = lane & 15, kq = lane >> 4, r0 = kq * 4;

    if (tid < 32) {
        int node = base + tid;
        sc[tid] = (node < n) ? NRscale[node] : 0.f;
    }
    __syncthreads();
    for (int idx = tid; idx < 32 * 80; idx += 512) {
        int r = idx / 80, c4 = (idx - r * 80) * 4;
        int node = base + r;
        float v[4] = {0.f, 0.f, 0.f, 0.f};
        if (c4 < DD && node < n) {
            short4v m4 = *(const short4v*)&NRm[(size_t)node * DD + c4];
            float s = sc[r];
            v[0] = (float)m4[0] * s; v[1] = (float)m4[1] * s;
            v[2] = (float)m4[2] * s; v[3] = (float)m4[3] * s;
        }
        short4v hh, ll;
#pragma unroll
        for (int q = 0; q < 4; ++q) {
            u16 h = f2bf(v[q]);
            hh[q] = (short)h;
            ll[q] = (short)f2bf(v[q] - bf2f(h));
        }
        *(short4v*)&nbh[r * 328 + c4] = hh;
        *(short4v*)&nbl[r * 328 + c4] = ll;
    }
    __syncthreads();

    {
        f32x4 acc[2][5];
#pragma unroll
        for (int s = 0; s < 2; ++s)
#pragma unroll
            for (int i = 0; i < 5; ++i) acc[s][i] = (f32x4){0.f, 0.f, 0.f, 0.f};
        const bool act5 = (wv + 32) < NT2;
        for (int ks = 0; ks < NK2; ++ks) {
            short8 bh[5], bl[5];
#pragma unroll
            for (int i = 0; i < 5; ++i) {
                int t = wv + 8 * i;
                if (i < 4 || act5) {
                    const short* bp = W1f + (((size_t)t * NK2 + ks) << 10) + lane * 8;
                    bh[i] = *(const short8*)bp;
                    bl[i] = *(const short8*)(bp + 512);
                }
            }
            short8 ah0 = *(const short8*)&nbh[cl * 328 + kq * 8 + ks * 32];
            short8 al0 = *(const short8*)&nbl[cl * 328 + kq * 8 + ks * 32];
            short8 ah1 = *(const short8*)&nbh[(16 + cl) * 328 + kq * 8 + ks * 32];
            short8 al1 = *(const short8*)&nbl[(16 + cl) * 328 + kq * 8 + ks * 32];
#pragma unroll
            for (int i = 0; i < 5; ++i)
                if (i < 4 || act5) {
                    acc[0][i] = __builtin_amdgcn_mfma_f32_16x16x32_bf16(ah0, bh[i], acc[0][i], 0, 0, 0);
                    acc[1][i] = __builtin_amdgcn_mfma_f32_16x16x32_bf16(ah1, bh[i], acc[1][i], 0, 0, 0);
                }
#pragma unroll
            for (int i = 0; i < 5; ++i)
                if (i < 4 || act5) {
                    acc[0][i] = __builtin_amdgcn_mfma_f32_16x16x32_bf16(ah0, bl[i], acc[0][i], 0, 0, 0);
                    acc[1][i] = __builtin_amdgcn_mfma_f32_16x16x32_bf16(ah1, bl[i], acc[1][i], 0, 0, 0);
                }
#pragma unroll
            for (int i = 0; i < 5; ++i)
                if (i < 4 || act5) {
                    acc[0][i] = __builtin_amdgcn_mfma_f32_16x16x32_bf16(al0, bh[i], acc[0][i], 0, 0, 0);
                    acc[1][i] = __builtin_amdgcn_mfma_f32_16x16x32_bf16(al1, bh[i], acc[1][i], 0, 0, 0);
                }
        }
        __syncthreads();   // nbuf fully read; safe to overwrite as tlf
#pragma unroll
        for (int s = 0; s < 2; ++s)
#pragma unroll
            for (int i = 0; i < 5; ++i) {
                int t = wv + 8 * i;
                if (t >= NT2) continue;
                int cg = t * 16 + cl;
                if (cg < DD2) {
                    float bb = b1[cg], ss = s1[cg], cc = sb1[cg];
#pragma unroll
                    for (int r = 0; r < 4; ++r)
                        tlf[(s * 16 + r0 + r) * 612 + cg] = fmaxf(fmaf(acc[s][i][r] + bb, ss, cc), 0.f);
                }
            }
    }
    __syncthreads();

    {
        const int wave = tid >> 6, ln = tid & 63;
#pragma unroll
        for (int rr = 0; rr < 4; ++rr) {
            int r = wave * 4 + rr;
            int node = base + r;
            float acc = 0.f;
            for (int j = ln; j < DD2; j += 64) acc = fmaf(tlf[r * 612 + j], W2[j], acc);
#pragma unroll
            for (int o = 32; o > 0; o >>= 1) acc += __shfl_down(acc, o);
            if (ln == 0 && node < n) gate[node] = acc + b2[0];
        }
    }
}

// ---------------- per-graph softmax-attention pooling -----------------------
__global__ void attn_pool_kernel(const float* __restrict__ gate,
                                 const short* __restrict__ NRm, const float* __restrict__ NRscale,
                                 const int* __restrict__ batch, float* __restrict__ rep, int n)
{
    __shared__ float red[320];
    __shared__ float bc[2];
    int g = blockIdx.x, t = threadIdx.x;
    int l0 = lower_bound_i(batch, n, g);
    int h0 = lower_bound_i(batch, n, g + 1);
    if (l0 >= h0) { if (t < DD) rep[(size_t)g * DD + t] = 0.f; return; }

    float m = -3.4e38f;
    for (int i = l0 + t; i < h0; i += 320) m = fmaxf(m, gate[i]);
    red[t] = m;
    __syncthreads();
    if (t < 64) {
        float mm = red[t];
        for (int s2 = t + 64; s2 < 320; s2 += 64) mm = fmaxf(mm, red[s2]);
#pragma unroll
        for (int o = 32; o > 0; o >>= 1) mm = fmaxf(mm, __shfl_down(mm, o));
        if (t == 0) bc[0] = mm;
    }
    __syncthreads();
    float gmax = bc[0];

    float ssum = 0.f;
    for (int i = l0 + t; i < h0; i += 320) ssum += expf(gate[i] - gmax);
    __syncthreads();
    red[t] = ssum;
    __syncthreads();
    if (t < 64) {
        float mm = red[t];
        for (int s2 = t + 64; s2 < 320; s2 += 64) mm += red[s2];
#pragma unroll
        for (int o = 32; o > 0; o >>= 1) mm += __shfl_down(mm, o);
        if (t == 0) bc[1] = mm;
    }
    __syncthreads();
    float inv = 1.0f / bc[1];

    if (t < DD) {
        float acc = 0.f;
        for (int i = l0; i < h0; ++i) {
            float w = expf(gate[i] - gmax) * inv;
            acc = fmaf(w, (float)NRm[(size_t)i * DD + t] * NRscale[i], acc);
        }
        rep[(size_t)g * DD + t] = acc;
    }
}

// ---------------- final projection ------------------------------------------
__global__ void final_kernel(const float* __restrict__ rep, const float* __restrict__ pW,
                             const float* __restrict__ pb, float* __restrict__ out)
{
    int g = blockIdx.x, lane = threadIdx.x;
    float a[NCLS] = {};
    for (int d = lane; d < DD; d += 64) {
        float r = rep[(size_t)g * DD + d];
#pragma unroll
        for (int c = 0; c < NCLS; ++c) a[c] = fmaf(r, pW[d * NCLS + c], a[c]);
    }
#pragma unroll
    for (int c = 0; c < NCLS; ++c) {
#pragma unroll
        for (int o = 32; o > 0; o >>= 1) a[c] += __shfl_down(a[c], o);
    }
    if (lane == 0) {
#pragma unroll
        for (int c = 0; c < NCLS; ++c) out[g * NCLS + c] = a[c] + pb[c];
    }
}

// ---------------------------------------------------------------------------
extern "C" void kernel_launch(void* const* d_in, const int* in_sizes, int n_in,
                              void* d_out, int out_size, void* d_ws, size_t ws_size,
                              hipStream_t stream)
{
    (void)n_in;
    const float* x      = (const float*)d_in[0];
    const int*   ei     = (const int*)d_in[1];
    const int*   braw   = (const int*)d_in[2];
    const float* enc_W  = (const float*)d_in[3];
    const float* enc_b  = (const float*)d_in[4];
    const float* eps    = (const float*)d_in[5];
    const float* cW1    = (const float*)d_in[6];
    const float* cb1    = (const float*)d_in[7];
    const float* cbn_s  = (const float*)d_in[8];
    const float* cbn_b  = (const float*)d_in[9];
    const float* cW2    = (const float*)d_in[10];
    const float* cb2    = (const float*)d_in[11];
    const float* bn_s   = (const float*)d_in[12];
    const float* bn_b   = (const float*)d_in[13];
    const float* vn0    = (const float*)d_in[14];
    const float* vW1    = (const float*)d_in[15];
    const float* vb1    = (const float*)d_in[16];
    const float* vbn1_s = (const float*)d_in[17];
    const float* vbn1_b = (const float*)d_in[18];
    const float* vW2    = (const float*)d_in[19];
    const float* vb2    = (const float*)d_in[20];
    const float* vbn2_s = (const float*)d_in[21];
    const float* vbn2_b = (const float*)d_in[22];
    const float* gW1    = (const float*)d_in[23];
    const float* gb1    = (const float*)d_in[24];
    const float* gbn_s  = (const float*)d_in[25];
    const float* gbn_b  = (const float*)d_in[26];
    const float* gW2    = (const float*)d_in[27];
    const float* gb2    = (const float*)d_in[28];
    const float* pW     = (const float*)d_in[29];
    const float* pb     = (const float*)d_in[30];
    float* out = (float*)d_out;

    const int N = in_sizes[0] / DIN;
    const int E = NEDGES;
    int fe = in_sizes[1] / (2 * E);
    if (fe < 1) fe = 1; if (fe > 2) fe = 2;

    // ---- workspace carve ----
    char* wsp = (char*)d_ws;
    size_t off = 0;
    auto carve = [&](size_t nbytes) -> void* {
        void* p = (void*)(wsp + off);
        off += ((nbytes + 255) / 256) * 256;
        return p;
    };
    u16*   Ahi     = (u16*)  carve((size_t)N * DD * 2);
    u8*    Alo     = (u8*)   carve((size_t)N * DD);
    u16*   Bhi     = (u16*)  carve((size_t)N * DD * 2);
    u8*    Blo     = (u8*)   carve((size_t)N * DD);
    short* NRm     = (short*)carve((size_t)N * DD * 2);
    float* NRscale = (float*)carve((size_t)N * 4);
    float* vnBuf   = (float*)carve((size_t)NGRAPH * DD * 4);
    float* vtmpBuf = (float*)carve((size_t)NGRAPH * DD * 4);
    float* repBuf  = (float*)carve((size_t)NGRAPH * DD * 4);
    float* gateBuf = (float*)carve((size_t)N * 4);
    int*   batch32 = (int*)  carve((size_t)N * 4);
    int*   row_ptr = (int*)  carve(((size_t)N + 1) * 4);
    int*   cursor  = (int*)  carve((size_t)N * 4);
    int*   col_idx = (int*)  carve((size_t)E * 4);
    short* W1f     = (short*)carve((size_t)NLAYER * W1F_SZ * 2);
    short* W2f     = (short*)carve((size_t)NLAYER * W1F_SZ * 2);
    short* gW1f    = (short*)carve((size_t)W1F_SZ * 2);

    if (off > ws_size) {
        diag_kernel<<<(out_size + 255) / 256, 256, 0, stream>>>(out, out_size, (float)ws_size);
        return;
    }

    // ---- weight packing ----
    const int pkBlocks = (NT2 * NK2 * 64 + 255) / 256;
    for (int l = 0; l < NLAYER; ++l) {
        packW_kernel<<<pkBlocks, 256, 0, stream>>>(cW1 + (size_t)l * DD * DD2, DD, DD2,
                                                   NT2, NK2, W1f + (size_t)l * W1F_SZ);
        packW_kernel<<<pkBlocks, 256, 0, stream>>>(cW2 + (size_t)l * DD2 * DD, DD2, DD,
                                                   NT3, NK3, W2f + (size_t)l * W1F_SZ);
    }
    packW_kernel<<<pkBlocks, 256, 0, stream>>>(gW1, DD, DD2, NT2, NK2, gW1f);

    bconv_kernel<<<(N + 255) / 256, 256, 0, stream>>>(braw, N, batch32);

    (void)hipMemsetAsync(cursor, 0, (size_t)N * 4, stream);
    deg_kernel<<<(E + 255) / 256, 256, 0, stream>>>(ei, fe, E, cursor);
    scan_kernel<<<1, 1024, 0, stream>>>(cursor, row_ptr, N);
    (void)hipMemcpyAsync(cursor, row_ptr, (size_t)N * 4, hipMemcpyDeviceToDevice, stream);
    scatter_kernel<<<(E + 255) / 256, 256, 0, stream>>>(ei, fe, E, cursor, col_idx);

    vn_init_kernel<<<(NGRAPH * DD + 255) / 256, 256, 0, stream>>>(vnBuf, vn0);

    const int nblk32 = (N + BR - 1) / BR;
    const int nblkM  = (N + BRM - 1) / BRM;
    const int nblk4  = (N + 3) / 4;

    encoder_kernel<<<nblk32, 1024, 0, stream>>>(x, enc_W, enc_b, Ahi, Alo, NRm, NRscale, N);

    u16 *Phi = Ahi, *Qhi = Bhi; u8 *Plo = Alo, *Qlo = Blo;
    for (int l = 0; l < NLAYER; ++l) {
        const bool hasVn = (l < NLAYER - 1);
        if (hasVn)
            vtmp_kernel<<<NGRAPH, 320, 0, stream>>>(Phi, Plo, batch32, vnBuf, vtmpBuf, N);
        agg_kernel<<<nblk4, 256, 0, stream>>>(Phi, Plo, Qhi, Qlo, row_ptr, col_idx, eps, l, N);
        if (hasVn)
            vn_mlp_kernel<<<NGRAPH, 512, 0, stream>>>(
                vtmpBuf,
                vW1 + (size_t)l * DD * DD2, vb1 + (size_t)l * DD2,
                vbn1_s + (size_t)l * DD2, vbn1_b + (size_t)l * DD2,
                vW2 + (size_t)l * DD2 * DD, vb2 + (size_t)l * DD,
                vbn2_s + (size_t)l * DD, vbn2_b + (size_t)l * DD,
                vnBuf);
        mlp_kernel<<<nblkM, 512, 0, stream>>>(
            Qhi, Qlo, NRm, NRscale,
            W1f + (size_t)l * W1F_SZ, cb1 + (size_t)l * DD2,
            cbn_s + (size_t)l * DD2, cbn_b + (size_t)l * DD2,
            W2f + (size_t)l * W1F_SZ, cb2 + (size_t)l * DD,
            bn_s + (size_t)l * DD, bn_b + (size_t)l * DD,
            hasVn ? 1 : 0,
            hasVn ? vnBuf : (const float*)nullptr, batch32,
            hasVn ? 1 : 0, N);
        u16* th = Phi; Phi = Qhi; Qhi = th;
        u8*  tb = Plo; Plo = Qlo; Qlo = tb;
    }

    gate_kernel<<<nblkM, 512, 0, stream>>>(NRm, NRscale, gW1f, gb1, gbn_s, gbn_b,
                                           gW2, gb2, gateBuf, N);
    attn_pool_kernel<<<NGRAPH, 320, 0, stream>>>(gateBuf, NRm, NRscale, batch32, repBuf, N);
    final_kernel<<<NGRAPH, 64, 0, stream>>>(repBuf, pW, pb, out);
}

// Round 21
// 3789.291 us; speedup vs baseline: 1.1984x; 1.0329x over previous
//
#include <hip/hip_runtime.h>
#include <cstddef>

#define NGRAPH 1000
#define NEDGES 1600000
#define DD     300
#define DD2    600
#define DIN    128
#define NLAYER 5
#define NCLS   10
#define BR     32
#define BRM    32

// MFMA fragment geometry
#define NT2 38
#define NK2 10
#define NT3 19
#define NK3 19
#define WFRAG 1024
#define W1F_SZ (NT2*NK2*WFRAG)

typedef unsigned short u16;
typedef unsigned char  u8;
typedef unsigned int   u32;
typedef __attribute__((ext_vector_type(8))) short short8;
typedef __attribute__((ext_vector_type(4))) short short4v;
typedef __attribute__((ext_vector_type(4))) float f32x4;

// ---------------- bf16 helpers ----------------------------------------------
__device__ __forceinline__ u16 f2bf(float f) {
    u32 u; __builtin_memcpy(&u, &f, 4);
    u = (u + 0x7FFFu + ((u >> 16) & 1u)) >> 16;
    return (u16)u;
}
__device__ __forceinline__ float bf2f(u16 h) {
    u32 u = ((u32)h) << 16;
    float f; __builtin_memcpy(&f, &u, 4); return f;
}

// ---------------- fp24 storage helpers (hi u16 plane + lo u8 plane) --------
__device__ __forceinline__ float ld24(const u16* __restrict__ hi, const u8* __restrict__ lo,
                                      size_t idx) {
    u32 u = ((u32)hi[idx] << 16) | ((u32)lo[idx] << 8);
    float f; __builtin_memcpy(&f, &u, 4); return f;
}
__device__ __forceinline__ void st24(u16* __restrict__ hi, u8* __restrict__ lo,
                                     size_t idx, float f) {
    u32 u; __builtin_memcpy(&u, &f, 4);
    u32 r = u + 0x7Fu + ((u >> 8) & 1u);
    hi[idx] = (u16)(r >> 16); lo[idx] = (u8)(r >> 8);
}
__device__ __forceinline__ void ld24x4(const u16* __restrict__ hi, const u8* __restrict__ lo,
                                       size_t idx, float o[4]) {
    ushort4 h = *(const ushort4*)(hi + idx);
    uchar4  l = *(const uchar4*)(lo + idx);
    u32 u0 = ((u32)h.x << 16) | ((u32)l.x << 8);
    u32 u1 = ((u32)h.y << 16) | ((u32)l.y << 8);
    u32 u2 = ((u32)h.z << 16) | ((u32)l.z << 8);
    u32 u3 = ((u32)h.w << 16) | ((u32)l.w << 8);
    __builtin_memcpy(&o[0], &u0, 4); __builtin_memcpy(&o[1], &u1, 4);
    __builtin_memcpy(&o[2], &u2, 4); __builtin_memcpy(&o[3], &u3, 4);
}
__device__ __forceinline__ void st24x4(u16* __restrict__ hi, u8* __restrict__ lo,
                                       size_t idx, const float v[4]) {
    u32 u[4];
#pragma unroll
    for (int q = 0; q < 4; ++q) {
        u32 t; __builtin_memcpy(&t, &v[q], 4);
        u[q] = t + 0x7Fu + ((t >> 8) & 1u);
    }
    ushort4 h; h.x = (u16)(u[0] >> 16); h.y = (u16)(u[1] >> 16);
    h.z = (u16)(u[2] >> 16); h.w = (u16)(u[3] >> 16);
    uchar4 l8; l8.x = (u8)(u[0] >> 8); l8.y = (u8)(u[1] >> 8);
    l8.z = (u8)(u[2] >> 8); l8.w = (u8)(u[3] >> 8);
    *(ushort4*)(hi + idx) = h;
    *(uchar4*)(lo + idx) = l8;
}

// ---------------------------------------------------------------------------
__global__ void diag_kernel(float* __restrict__ out, int n, float val)
{
    int i = blockIdx.x * 256 + threadIdx.x;
    if (i < n) out[i] = val;
}

__global__ void vn_init_kernel(float* __restrict__ vn, const float* __restrict__ vn0)
{
    int idx = blockIdx.x * 256 + threadIdx.x;
    if (idx < NGRAPH * DD) vn[idx] = vn0[idx % DD];
}

__global__ void bconv_kernel(const int* __restrict__ braw, int n, int* __restrict__ b32)
{
    int i = blockIdx.x * 256 + threadIdx.x;
    if (i >= n) return;
    int fs = (braw[n - 1] == 0) ? 2 : 1;
    b32[i] = braw[(size_t)i * fs];
}

// pack W [K x N] fp32 -> MFMA B-fragments, split bf16 hi/lo.
__global__ void packW_kernel(const float* __restrict__ W, int K, int N,
                             int nT, int nK, short* __restrict__ dst)
{
    int idx = blockIdx.x * 256 + threadIdx.x;
    int total = nT * nK * 64;
    if (idx >= total) return;
    int lane = idx & 63;
    int tk = idx >> 6;
    int nn = (tk / nK) * 16 + (lane & 15);
    int k0 = (tk % nK) * 32 + (lane >> 4) * 8;
    short* o = dst + ((size_t)tk << 10) + lane * 8;
#pragma unroll
    for (int j = 0; j < 8; ++j) {
        float v = (nn < N && (k0 + j) < K) ? W[(size_t)(k0 + j) * N + nn] : 0.f;
        u16 h = f2bf(v);
        o[j] = (short)h;
        o[512 + j] = (short)f2bf(v - bf2f(h));
    }
}

// ---------------- CSR build -------------------------------------------------
__global__ void deg_kernel(const int* __restrict__ ei, int fe, int E, int* __restrict__ deg)
{
    int e = blockIdx.x * 256 + threadIdx.x;
    if (e < E) atomicAdd(&deg[ei[(size_t)fe * (E + e)]], 1);
}

__global__ void scan_kernel(const int* __restrict__ deg, int* __restrict__ row_ptr, int n)
{
    __shared__ int sd[1024];
    int t = threadIdx.x;
    int C = (n + 1023) >> 10;
    int i0 = t * C, i1 = i0 + C; if (i1 > n) i1 = n; if (i0 > n) i0 = n;
    int s = 0;
    for (int i = i0; i < i1; ++i) s += deg[i];
    sd[t] = s;
    __syncthreads();
    for (int o = 1; o < 1024; o <<= 1) {
        int x = (t >= o) ? sd[t - o] : 0;
        __syncthreads();
        sd[t] += x;
        __syncthreads();
    }
    int run = (t == 0) ? 0 : sd[t - 1];
    for (int i = i0; i < i1; ++i) { row_ptr[i] = run; run += deg[i]; }
    if (t == 1023) row_ptr[n] = sd[1023];
}

__global__ void scatter_kernel(const int* __restrict__ ei, int fe, int E,
                               int* __restrict__ cursor, int* __restrict__ col_idx)
{
    int e = blockIdx.x * 256 + threadIdx.x;
    if (e < E) {
        int d = ei[(size_t)fe * (E + e)];
        int s = ei[(size_t)fe * e];
        int p = atomicAdd(&cursor[d], 1);
        col_idx[p] = s;
    }
}

__device__ __forceinline__ int lower_bound_i(const int* __restrict__ arr, int n, int key)
{
    int lo = 0, hi = n;
    while (lo < hi) {
        int mid = (lo + hi) >> 1;
        if (arr[mid] < key) lo = mid + 1; else hi = mid;
    }
    return lo;
}

// ---------------- encoder (writes h0 = hl0 since vn0 = 0) --------------------
__global__ __launch_bounds__(1024)
void encoder_kernel(const float* __restrict__ x, const float* __restrict__ W,
                    const float* __restrict__ b,
                    u16* __restrict__ Ahi, u8* __restrict__ Alo,
                    short* __restrict__ NRm, float* __restrict__ NRscale, int n)
{
    __shared__ float xs[BR][DIN];
    __shared__ float wmax[16][8];
    __shared__ float rowS[BR];
    const int tid = threadIdx.x;
    const int base = blockIdx.x * BR;
    for (int idx = tid; idx < BR * DIN; idx += 1024) {
        int r = idx >> 7, c = idx & 127;
        int node = base + r;
        xs[r][c] = (node < n) ? x[(size_t)node * DIN + c] : 0.f;
    }
    __syncthreads();
    const int rq = tid >> 8, ct = tid & 255;
    const int wid = tid >> 6, lane = tid & 63;
    const int j0 = ct; const bool has1 = ct < (DD - 256); const int j1 = ct + 256;
    float acc[8][2] = {};
    for (int k = 0; k < DIN; ++k) {
        const float* wr = W + (size_t)k * DD;
        float w0 = wr[j0], w1 = has1 ? wr[j1] : 0.f;
#pragma unroll
        for (int i = 0; i < 8; ++i) {
            float a = xs[rq * 8 + i][k];
            acc[i][0] = fmaf(a, w0, acc[i][0]);
            acc[i][1] = fmaf(a, w1, acc[i][1]);
        }
    }
    float bb0 = b[j0], bb1 = has1 ? b[j1] : 0.f;
    float v0[8], v1[8], lm[8];
#pragma unroll
    for (int i = 0; i < 8; ++i) {
        v0[i] = acc[i][0] + bb0;
        v1[i] = has1 ? (acc[i][1] + bb1) : 0.f;
        lm[i] = fmaxf(fabsf(v0[i]), fabsf(v1[i]));
    }
#pragma unroll
    for (int o = 32; o > 0; o >>= 1)
#pragma unroll
        for (int i = 0; i < 8; ++i) lm[i] = fmaxf(lm[i], __shfl_xor(lm[i], o));
    if (lane == 0)
#pragma unroll
        for (int i = 0; i < 8; ++i) wmax[wid][i] = lm[i];
    __syncthreads();
    if (ct < 8) {
        int r = rq * 8 + ct;
        float m = fmaxf(fmaxf(wmax[4 * rq][ct], wmax[4 * rq + 1][ct]),
                        fmaxf(wmax[4 * rq + 2][ct], wmax[4 * rq + 3][ct]));
        float S = fmaxf(m, 1e-30f) / 32767.f;
        rowS[r] = S;
        if (base + r < n) NRscale[base + r] = S;
    }
    __syncthreads();
#pragma unroll
    for (int i = 0; i < 8; ++i) {
        int r = rq * 8 + i;
        int node = base + r;
        if (node >= n) continue;
        float S = rowS[r];
        size_t idx = (size_t)node * DD + j0;
        st24(Ahi, Alo, idx, v0[i]);
        NRm[idx] = (short)rintf(v0[i] / S);
        if (has1) {
            st24(Ahi, Alo, idx + 256, v1[i]);
            NRm[idx + 256] = (short)rintf(v1[i] / S);
        }
    }
}

// ---------------- fused agg + vn pipeline (heterogeneous grid) ---------------
// blocks [0, vnBlocks): per-graph vtmp + vn MLP (vn_{l+1} <- MLP(sum hl + vn_l))
// blocks [vnBlocks, ...): edge-gather aggregate (x2 unrolled), 4 nodes/block
__global__ __launch_bounds__(256)
void agg_vn_kernel(const u16* __restrict__ Phi, const u8* __restrict__ Plo,
                   u16* __restrict__ Qhi, u8* __restrict__ Qlo,
                   const int* __restrict__ row_ptr, const int* __restrict__ col_idx,
                   const float* __restrict__ eps, int l, int n,
                   int vnBlocks, const int* __restrict__ batch,
                   const float* __restrict__ vW1, const float* __restrict__ vb1,
                   const float* __restrict__ vs1, const float* __restrict__ vsb1,
                   const float* __restrict__ vW2, const float* __restrict__ vb2,
                   const float* __restrict__ vs2, const float* __restrict__ vsb2,
                   float* __restrict__ vn)
{
    if ((int)blockIdx.x < vnBlocks) {
        // ---- vn path: one block per graph ----
        __shared__ float vt[DD];
        __shared__ float us[DD2];
        const int g = blockIdx.x;
        const int t = threadIdx.x;
        const int l0 = lower_bound_i(batch, n, g);
        const int h0 = lower_bound_i(batch, n, g + 1);
        for (int c = t; c < DD; c += 256) {
            float a0 = 0.f, a1 = 0.f, a2 = 0.f, a3 = 0.f;
            int i = l0;
            for (; i + 3 < h0; i += 4) {
                a0 += ld24(Phi, Plo, (size_t)(i + 0) * DD + c);
                a1 += ld24(Phi, Plo, (size_t)(i + 1) * DD + c);
                a2 += ld24(Phi, Plo, (size_t)(i + 2) * DD + c);
                a3 += ld24(Phi, Plo, (size_t)(i + 3) * DD + c);
            }
            for (; i < h0; ++i) a0 += ld24(Phi, Plo, (size_t)i * DD + c);
            vt[c] = ((a0 + a1) + (a2 + a3)) + vn[(size_t)g * DD + c];
        }
        __syncthreads();
        for (int j = t; j < DD2; j += 256) {
            float acc = 0.f;
            for (int k = 0; k < DD; ++k) acc = fmaf(vt[k], vW1[(size_t)k * DD2 + j], acc);
            us[j] = fmaxf(fmaf(acc + vb1[j], vs1[j], vsb1[j]), 0.f);
        }
        __syncthreads();
        for (int j = t; j < DD; j += 256) {
            float acc = 0.f;
            for (int k = 0; k < DD2; ++k) acc = fmaf(us[k], vW2[(size_t)k * DD + j], acc);
            vn[(size_t)g * DD + j] = fmaxf(fmaf(acc + vb2[j], vs2[j], vsb2[j]), 0.f);
        }
        return;
    }

    // ---- agg path (x2 unrolled edge loop) ----
    int node = ((int)blockIdx.x - vnBlocks) * 4 + (threadIdx.x >> 6);
    int lane = threadIdx.x & 63;
    if (node >= n) return;
    const float ep = 1.0f + eps[l];
    const bool two = (lane < 11);
    float a0[4] = {0.f, 0.f, 0.f, 0.f}, a1[4] = {0.f, 0.f, 0.f, 0.f};
    float b0[4] = {0.f, 0.f, 0.f, 0.f}, b1[4] = {0.f, 0.f, 0.f, 0.f};
    int e0 = row_ptr[node], e1 = row_ptr[node + 1];
    int e = e0;
    for (; e + 1 < e1; e += 2) {
        int s0 = col_idx[e], s1 = col_idx[e + 1];
        size_t rb0 = (size_t)s0 * DD, rb1 = (size_t)s1 * DD;
        float v[4], w[4];
        ld24x4(Phi, Plo, rb0 + lane * 4, v);
        ld24x4(Phi, Plo, rb1 + lane * 4, w);
        a0[0] += v[0]; a0[1] += v[1]; a0[2] += v[2]; a0[3] += v[3];
        b0[0] += w[0]; b0[1] += w[1]; b0[2] += w[2]; b0[3] += w[3];
        if (two) {
            ld24x4(Phi, Plo, rb0 + 256 + lane * 4, v);
            ld24x4(Phi, Plo, rb1 + 256 + lane * 4, w);
            a1[0] += v[0]; a1[1] += v[1]; a1[2] += v[2]; a1[3] += v[3];
            b1[0] += w[0]; b1[1] += w[1]; b1[2] += w[2]; b1[3] += w[3];
        }
    }
    if (e < e1) {
        int s0 = col_idx[e];
        size_t rb0 = (size_t)s0 * DD;
        float v[4];
        ld24x4(Phi, Plo, rb0 + lane * 4, v);
        a0[0] += v[0]; a0[1] += v[1]; a0[2] += v[2]; a0[3] += v[3];
        if (two) {
            ld24x4(Phi, Plo, rb0 + 256 + lane * 4, v);
            a1[0] += v[0]; a1[1] += v[1]; a1[2] += v[2]; a1[3] += v[3];
        }
    }
    size_t ob = (size_t)node * DD;
    float v[4], o[4];
    ld24x4(Phi, Plo, ob + lane * 4, v);
#pragma unroll
    for (int q = 0; q < 4; ++q) o[q] = fmaf(ep, v[q], a0[q] + b0[q]);
    st24x4(Qhi, Qlo, ob + lane * 4, o);
    if (two) {
        ld24x4(Phi, Plo, ob + 256 + lane * 4, v);
#pragma unroll
        for (int q = 0; q < 4; ++q) o[q] = fmaf(ep, v[q], a1[q] + b1[q]);
        st24x4(Qhi, Qlo, ob + 256 + lane * 4, o);
    }
}

// ---------------- MLP via split-bf16 MFMA (BRM=32, LDS-aliased phases) -------
__global__ __launch_bounds__(512)
void mlp_kernel(u16* __restrict__ Qhi, u8* __restrict__ Qlo,
                short* __restrict__ NRm, float* __restrict__ NRscale,
                const short* __restrict__ W1f, const float* __restrict__ b1,
                const float* __restrict__ s1, const float* __restrict__ sb1,
                const short* __restrict__ W2f, const float* __restrict__ b2,
                const float* __restrict__ s2, const float* __restrict__ sb2,
                int relu2, const float* __restrict__ vnp,
                const int* __restrict__ batch, int writeQ, int n)
{
    __shared__ char uni[78848];
    __shared__ float rowM[32], rowSo[32], rowSn[32];
    short* agh = (short*)uni;               // [32][328]
    short* agl = (short*)(uni + 20992);     // [32][328]
    short* tlh = (short*)uni;               // [32][616]
    short* tll = (short*)(uni + 39424);     // [32][616]
    float* outb = (float*)uni;              // [32][304]

    const int tid = threadIdx.x;
    const int base = blockIdx.x * BRM;
    const int wv = tid >> 6, lane = tid & 63;
    const int cl = lane & 15, kq = lane >> 4, r0 = kq * 4;

    // stage A as split bf16 (vectorized 4-col quads; zeros beyond DD / n)
    for (int idx = tid; idx < 32 * 80; idx += 512) {
        int r = idx / 80, c4 = (idx - r * 80) * 4;
        int node = base + r;
        float v[4] = {0.f, 0.f, 0.f, 0.f};
        if (c4 < DD && node < n) ld24x4(Qhi, Qlo, (size_t)node * DD + c4, v);
        short4v hh, ll;
#pragma unroll
        for (int q = 0; q < 4; ++q) {
            u16 h = f2bf(v[q]);
            hh[q] = (short)h;
            ll[q] = (short)f2bf(v[q] - bf2f(h));
        }
        *(short4v*)&agh[r * 328 + c4] = hh;
        *(short4v*)&agl[r * 328 + c4] = ll;
    }
    __syncthreads();

    // phase 2: t = relu(bn1(ag @ W1))  [32 x 600]
    {
        f32x4 acc[2][5];
#pragma unroll
        for (int s = 0; s < 2; ++s)
#pragma unroll
            for (int i = 0; i < 5; ++i) acc[s][i] = (f32x4){0.f, 0.f, 0.f, 0.f};
        const bool act5 = (wv + 32) < NT2;
        for (int ks = 0; ks < NK2; ++ks) {
            short8 bh[5], bl[5];
#pragma unroll
            for (int i = 0; i < 5; ++i) {
                int t = wv + 8 * i;
                if (i < 4 || act5) {
                    const short* bp = W1f + (((size_t)t * NK2 + ks) << 10) + lane * 8;
                    bh[i] = *(const short8*)bp;
                    bl[i] = *(const short8*)(bp + 512);
                }
            }
            short8 ah0 = *(const short8*)&agh[cl * 328 + kq * 8 + ks * 32];
            short8 al0 = *(const short8*)&agl[cl * 328 + kq * 8 + ks * 32];
            short8 ah1 = *(const short8*)&agh[(16 + cl) * 328 + kq * 8 + ks * 32];
            short8 al1 = *(const short8*)&agl[(16 + cl) * 328 + kq * 8 + ks * 32];
#pragma unroll
            for (int i = 0; i < 5; ++i)
                if (i < 4 || act5) {
                    acc[0][i] = __builtin_amdgcn_mfma_f32_16x16x32_bf16(ah0, bh[i], acc[0][i], 0, 0, 0);
                    acc[1][i] = __builtin_amdgcn_mfma_f32_16x16x32_bf16(ah1, bh[i], acc[1][i], 0, 0, 0);
                }
#pragma unroll
            for (int i = 0; i < 5; ++i)
                if (i < 4 || act5) {
                    acc[0][i] = __builtin_amdgcn_mfma_f32_16x16x32_bf16(ah0, bl[i], acc[0][i], 0, 0, 0);
                    acc[1][i] = __builtin_amdgcn_mfma_f32_16x16x32_bf16(ah1, bl[i], acc[1][i], 0, 0, 0);
                }
#pragma unroll
            for (int i = 0; i < 5; ++i)
                if (i < 4 || act5) {
                    acc[0][i] = __builtin_amdgcn_mfma_f32_16x16x32_bf16(al0, bh[i], acc[0][i], 0, 0, 0);
                    acc[1][i] = __builtin_amdgcn_mfma_f32_16x16x32_bf16(al1, bh[i], acc[1][i], 0, 0, 0);
                }
        }
        __syncthreads();   // agbuf fully read; safe to overwrite as tlbuf
        if (tid < 256) {
            int r = tid >> 3, c = 600 + (tid & 7);
            tlh[r * 616 + c] = 0; tll[r * 616 + c] = 0;
        }
#pragma unroll
        for (int s = 0; s < 2; ++s)
#pragma unroll
            for (int i = 0; i < 5; ++i) {
                int t = wv + 8 * i;
                if (t >= NT2) continue;
                int cg = t * 16 + cl;
                if (cg < DD2) {
                    float bb = b1[cg], ss = s1[cg], cc = sb1[cg];
#pragma unroll
                    for (int r = 0; r < 4; ++r) {
                        float xv = fmaxf(fmaf(acc[s][i][r] + bb, ss, cc), 0.f);
                        u16 h = f2bf(xv);
                        tlh[(s * 16 + r0 + r) * 616 + cg] = (short)h;
                        tll[(s * 16 + r0 + r) * 616 + cg] = (short)f2bf(xv - bf2f(h));
                    }
                }
            }
    }
    __syncthreads();

    // phase 3: out_raw = t @ W2  [32 x 300], K=608 (19 steps)
    {
        f32x4 acc[2][3];
#pragma unroll
        for (int s = 0; s < 2; ++s)
#pragma unroll
            for (int i = 0; i < 3; ++i) acc[s][i] = (f32x4){0.f, 0.f, 0.f, 0.f};
        const bool act3 = (wv + 16) < NT3;
        for (int ks = 0; ks < NK3; ++ks) {
            short8 bh[3], bl[3];
#pragma unroll
            for (int i = 0; i < 3; ++i) {
                int t = wv + 8 * i;
                if (i < 2 || act3) {
                    const short* bp = W2f + (((size_t)t * NK3 + ks) << 10) + lane * 8;
                    bh[i] = *(const short8*)bp;
                    bl[i] = *(const short8*)(bp + 512);
                }
            }
            short8 ah0 = *(const short8*)&tlh[cl * 616 + kq * 8 + ks * 32];
            short8 al0 = *(const short8*)&tll[cl * 616 + kq * 8 + ks * 32];
            short8 ah1 = *(const short8*)&tlh[(16 + cl) * 616 + kq * 8 + ks * 32];
            short8 al1 = *(const short8*)&tll[(16 + cl) * 616 + kq * 8 + ks * 32];
#pragma unroll
            for (int i = 0; i < 3; ++i)
                if (i < 2 || act3) {
                    acc[0][i] = __builtin_amdgcn_mfma_f32_16x16x32_bf16(ah0, bh[i], acc[0][i], 0, 0, 0);
                    acc[1][i] = __builtin_amdgcn_mfma_f32_16x16x32_bf16(ah1, bh[i], acc[1][i], 0, 0, 0);
                }
#pragma unroll
            for (int i = 0; i < 3; ++i)
                if (i < 2 || act3) {
                    acc[0][i] = __builtin_amdgcn_mfma_f32_16x16x32_bf16(ah0, bl[i], acc[0][i], 0, 0, 0);
                    acc[1][i] = __builtin_amdgcn_mfma_f32_16x16x32_bf16(ah1, bl[i], acc[1][i], 0, 0, 0);
                }
#pragma unroll
            for (int i = 0; i < 3; ++i)
                if (i < 2 || act3) {
                    acc[0][i] = __builtin_amdgcn_mfma_f32_16x16x32_bf16(al0, bh[i], acc[0][i], 0, 0, 0);
                    acc[1][i] = __builtin_amdgcn_mfma_f32_16x16x32_bf16(al1, bh[i], acc[1][i], 0, 0, 0);
                }
        }
        __syncthreads();   // tlbuf fully read; safe to overwrite as outb
#pragma unroll
        for (int s = 0; s < 2; ++s)
#pragma unroll
            for (int i = 0; i < 3; ++i) {
                int t = wv + 8 * i;
                if (t >= NT3) continue;
                int cg = t * 16 + cl;
#pragma unroll
                for (int r = 0; r < 4; ++r) outb[(s * 16 + r0 + r) * 304 + cg] = acc[s][i][r];
            }
    }
    __syncthreads();

    // epilogue (a): bn2 (+relu) in place + row max
    {
        const int rr = tid >> 4;
        const int qq = tid & 15;
        float lm = 0.f;
        for (int c = qq; c < DD; c += 16) {
            float v = fmaf(outb[rr * 304 + c] + b2[c], s2[c], sb2[c]);
            if (relu2) v = fmaxf(v, 0.f);
            outb[rr * 304 + c] = v;
            lm = fmaxf(lm, fabsf(v));
        }
#pragma unroll
        for (int o = 8; o > 0; o >>= 1) lm = fmaxf(lm, __shfl_xor(lm, o));
        if (qq == 0) rowM[rr] = lm;
    }
    __syncthreads();
    // epilogue (b): per-row scale update
    if (tid < 32) {
        int node = base + tid;
        float oS = (node < n) ? NRscale[node] : 0.f;
        float newM = fmaxf(rowM[tid], oS * 32767.f);
        float nS = fmaxf(newM, 1e-30f) / 32767.f;
        rowSo[tid] = oS; rowSn[tid] = nS;
        if (node < n) NRscale[node] = nS;
    }
    __syncthreads();
    // epilogue (c): vectorized store, 4-col quads (75 quads cover 300 cols)
    for (int idx = tid; idx < 32 * 75; idx += 512) {
        int r = idx / 75, c = (idx - r * 75) * 4;
        int node = base + r;
        if (node >= n) continue;
        float oS = rowSo[r], inv = 1.0f / rowSn[r];
        size_t gidx = (size_t)node * DD + c;
        float h0 = outb[r * 304 + c + 0];
        float h1 = outb[r * 304 + c + 1];
        float h2 = outb[r * 304 + c + 2];
        float h3 = outb[r * 304 + c + 3];
        if (writeQ) {
            float hl[4];
            if (vnp) {
                const float* vrow = vnp + (size_t)batch[node] * DD;
                float4 vv = *(const float4*)(vrow + c);
                hl[0] = h0 + vv.x; hl[1] = h1 + vv.y; hl[2] = h2 + vv.z; hl[3] = h3 + vv.w;
            } else {
                hl[0] = h0; hl[1] = h1; hl[2] = h2; hl[3] = h3;
            }
            st24x4(Qhi, Qlo, gidx, hl);
        }
        short4v old = *(const short4v*)&NRm[gidx];
        short4v nw;
        nw[0] = (short)rintf(fmaxf((float)old[0] * oS, h0) * inv);
        nw[1] = (short)rintf(fmaxf((float)old[1] * oS, h1) * inv);
        nw[2] = (short)rintf(fmaxf((float)old[2] * oS, h2) * inv);
        nw[3] = (short)rintf(fmaxf((float)old[3] * oS, h3) * inv);
        *(short4v*)&NRm[gidx] = nw;
    }
}

// ---------------- gate: MFMA phase-1 GEMM (BRM=32, LDS-aliased) + dot --------
__global__ __launch_bounds__(512)
void gate_kernel(const short* __restrict__ NRm, const float* __restrict__ NRscale,
                 const short* __restrict__ W1f, const float* __restrict__ b1,
                 const float* __restrict__ s1, const float* __restrict__ sb1,
                 const float* __restrict__ W2, const float* __restrict__ b2,
                 float* __restrict__ gate, int n)
{
    __shared__ char uni[78336];
    __shared__ float sc[32];
    short* nbh = (short*)uni;
    short* nbl = (short*)(uni + 20992);
    float* tlf = (float*)uni;   // [32][612]

    const int tid = threadIdx.x;
    const int base = blockIdx.x * BRM;
    const int wv = tid >> 6, lane = tid & 63;
    const int cl = lane & 15, kq = lane >> 4, r0 = kq * 4;

    if (tid < 32) {
        int node = base + tid;
        sc[tid] = (node < n) ? NRscale[node] : 0.f;
    }
    __syncthreads();
    for (int idx = tid; idx < 32 * 80; idx += 512) {
        int r = idx / 80, c4 = (idx - r * 80) * 4;
        int node = base + r;
        float v[4] = {0.f, 0.f, 0.f, 0.f};
        if (c4 < DD && node < n) {
            short4v m4 = *(const short4v*)&NRm[(size_t)node * DD + c4];
            float s = sc[r];
            v[0] = (float)m4[0] * s; v[1] = (float)m4[1] * s;
            v[2] = (float)m4[2] * s; v[3] = (float)m4[3] * s;
        }
        short4v hh, ll;
#pragma unroll
        for (int q = 0; q < 4; ++q) {
            u16 h = f2bf(v[q]);
            hh[q] = (short)h;
            ll[q] = (short)f2bf(v[q] - bf2f(h));
        }
        *(short4v*)&nbh[r * 328 + c4] = hh;
        *(short4v*)&nbl[r * 328 + c4] = ll;
    }
    __syncthreads();

    {
        f32x4 acc[2][5];
#pragma unroll
        for (int s = 0; s < 2; ++s)
#pragma unroll
            for (int i = 0; i < 5; ++i) acc[s][i] = (f32x4){0.f, 0.f, 0.f, 0.f};
        const bool act5 = (wv + 32) < NT2;
        for (int ks = 0; ks < NK2; ++ks) {
            short8 bh[5], bl[5];
#pragma unroll
            for (int i = 0; i < 5; ++i) {
                int t = wv + 8 * i;
                if (i < 4 || act5) {
                    const short* bp = W1f + (((size_t)t * NK2 + ks) << 10) + lane * 8;
                    bh[i] = *(const short8*)bp;
                    bl[i] = *(const short8*)(bp + 512);
                }
            }
            short8 ah0 = *(const short8*)&nbh[cl * 328 + kq * 8 + ks * 32];
            short8 al0 = *(const short8*)&nbl[cl * 328 + kq * 8 + ks * 32];
            short8 ah1 = *(const short8*)&nbh[(16 + cl) * 328 + kq * 8 + ks * 32];
            short8 al1 = *(const short8*)&nbl[(16 + cl) * 328 + kq * 8 + ks * 32];
#pragma unroll
            for (int i = 0; i < 5; ++i)
                if (i < 4 || act5) {
                    acc[0][i] = __builtin_amdgcn_mfma_f32_16x16x32_bf16(ah0, bh[i], acc[0][i], 0, 0, 0);
                    acc[1][i] = __builtin_amdgcn_mfma_f32_16x16x32_bf16(ah1, bh[i], acc[1][i], 0, 0, 0);
                }
#pragma unroll
            for (int i = 0; i < 5; ++i)
                if (i < 4 || act5) {
                    acc[0][i] = __builtin_amdgcn_mfma_f32_16x16x32_bf16(ah0, bl[i], acc[0][i], 0, 0, 0);
                    acc[1][i] = __builtin_amdgcn_mfma_f32_16x16x32_bf16(ah1, bl[i], acc[1][i], 0, 0, 0);
                }
#pragma unroll
            for (int i = 0; i < 5; ++i)
                if (i < 4 || act5) {
                    acc[0][i] = __builtin_amdgcn_mfma_f32_16x16x32_bf16(al0, bh[i], acc[0][i], 0, 0, 0);
                    acc[1][i] = __builtin_amdgcn_mfma_f32_16x16x32_bf16(al1, bh[i], acc[1][i], 0, 0, 0);
                }
        }
        __syncthreads();   // nbuf fully read; safe to overwrite as tlf
#pragma unroll
        for (int s = 0; s < 2; ++s)
#pragma unroll
            for (int i = 0; i < 5; ++i) {
                int t = wv + 8 * i;
                if (t >= NT2) continue;
                int cg = t * 16 + cl;
                if (cg < DD2) {
                    float bb = b1[cg], ss = s1[cg], cc = sb1[cg];
#pragma unroll
                    for (int r = 0; r < 4; ++r)
                        tlf[(s * 16 + r0 + r) * 612 + cg] = fmaxf(fmaf(acc[s][i][r] + bb, ss, cc), 0.f);
                }
            }
    }
    __syncthreads();

    {
        const int wave = tid >> 6, ln = tid & 63;
#pragma unroll
        for (int rr = 0; rr < 4; ++rr) {
            int r = wave * 4 + rr;
            int node = base + r;
            float acc = 0.f;
            for (int j = ln; j < DD2; j += 64) acc = fmaf(tlf[r * 612 + j], W2[j], acc);
#pragma unroll
            for (int o = 32; o > 0; o >>= 1) acc += __shfl_down(acc, o);
            if (ln == 0 && node < n) gate[node] = acc + b2[0];
        }
    }
}

// ---------------- per-graph softmax-attention pooling -----------------------
__global__ void attn_pool_kernel(const float* __restrict__ gate,
                                 const short* __restrict__ NRm, const float* __restrict__ NRscale,
                                 const int* __restrict__ batch, float* __restrict__ rep, int n)
{
    __shared__ float red[320];
    __shared__ float bc[2];
    int g = blockIdx.x, t = threadIdx.x;
    int l0 = lower_bound_i(batch, n, g);
    int h0 = lower_bound_i(batch, n, g + 1);
    if (l0 >= h0) { if (t < DD) rep[(size_t)g * DD + t] = 0.f; return; }

    float m = -3.4e38f;
    for (int i = l0 + t; i < h0; i += 320) m = fmaxf(m, gate[i]);
    red[t] = m;
    __syncthreads();
    if (t < 64) {
        float mm = red[t];
        for (int s2 = t + 64; s2 < 320; s2 += 64) mm = fmaxf(mm, red[s2]);
#pragma unroll
        for (int o = 32; o > 0; o >>= 1) mm = fmaxf(mm, __shfl_down(mm, o));
        if (t == 0) bc[0] = mm;
    }
    __syncthreads();
    float gmax = bc[0];

    float ssum = 0.f;
    for (int i = l0 + t; i < h0; i += 320) ssum += expf(gate[i] - gmax);
    __syncthreads();
    red[t] = ssum;
    __syncthreads();
    if (t < 64) {
        float mm = red[t];
        for (int s2 = t + 64; s2 < 320; s2 += 64) mm += red[s2];
#pragma unroll
        for (int o = 32; o > 0; o >>= 1) mm += __shfl_down(mm, o);
        if (t == 0) bc[1] = mm;
    }
    __syncthreads();
    float inv = 1.0f / bc[1];

    if (t < DD) {
        float acc = 0.f;
        for (int i = l0; i < h0; ++i) {
            float w = expf(gate[i] - gmax) * inv;
            acc = fmaf(w, (float)NRm[(size_t)i * DD + t] * NRscale[i], acc);
        }
        rep[(size_t)g * DD + t] = acc;
    }
}

// ---------------- final projection ------------------------------------------
__global__ void final_kernel(const float* __restrict__ rep, const float* __restrict__ pW,
                             const float* __restrict__ pb, float* __restrict__ out)
{
    int g = blockIdx.x, lane = threadIdx.x;
    float a[NCLS] = {};
    for (int d = lane; d < DD; d += 64) {
        float r = rep[(size_t)g * DD + d];
#pragma unroll
        for (int c = 0; c < NCLS; ++c) a[c] = fmaf(r, pW[d * NCLS + c], a[c]);
    }
#pragma unroll
    for (int c = 0; c < NCLS; ++c) {
#pragma unroll
        for (int o = 32; o > 0; o >>= 1) a[c] += __shfl_down(a[c], o);
    }
    if (lane == 0) {
#pragma unroll
        for (int c = 0; c < NCLS; ++c) out[g * NCLS + c] = a[c] + pb[c];
    }
}

// ---------------------------------------------------------------------------
extern "C" void kernel_launch(void* const* d_in, const int* in_sizes, int n_in,
                              void* d_out, int out_size, void* d_ws, size_t ws_size,
                              hipStream_t stream)
{
    (void)n_in;
    const float* x      = (const float*)d_in[0];
    const int*   ei     = (const int*)d_in[1];
    const int*   braw   = (const int*)d_in[2];
    const float* enc_W  = (const float*)d_in[3];
    const float* enc_b  = (const float*)d_in[4];
    const float* eps    = (const float*)d_in[5];
    const float* cW1    = (const float*)d_in[6];
    const float* cb1    = (const float*)d_in[7];
    const float* cbn_s  = (const float*)d_in[8];
    const float* cbn_b  = (const float*)d_in[9];
    const float* cW2    = (const float*)d_in[10];
    const float* cb2    = (const float*)d_in[11];
    const float* bn_s   = (const float*)d_in[12];
    const float* bn_b   = (const float*)d_in[13];
    const float* vn0    = (const float*)d_in[14];
    const float* vW1    = (const float*)d_in[15];
    const float* vb1    = (const float*)d_in[16];
    const float* vbn1_s = (const float*)d_in[17];
    const float* vbn1_b = (const float*)d_in[18];
    const float* vW2    = (const float*)d_in[19];
    const float* vb2    = (const float*)d_in[20];
    const float* vbn2_s = (const float*)d_in[21];
    const float* vbn2_b = (const float*)d_in[22];
    const float* gW1    = (const float*)d_in[23];
    const float* gb1    = (const float*)d_in[24];
    const float* gbn_s  = (const float*)d_in[25];
    const float* gbn_b  = (const float*)d_in[26];
    const float* gW2    = (const float*)d_in[27];
    const float* gb2    = (const float*)d_in[28];
    const float* pW     = (const float*)d_in[29];
    const float* pb     = (const float*)d_in[30];
    float* out = (float*)d_out;

    const int N = in_sizes[0] / DIN;
    const int E = NEDGES;
    int fe = in_sizes[1] / (2 * E);
    if (fe < 1) fe = 1; if (fe > 2) fe = 2;

    // ---- workspace carve ----
    char* wsp = (char*)d_ws;
    size_t off = 0;
    auto carve = [&](size_t nbytes) -> void* {
        void* p = (void*)(wsp + off);
        off += ((nbytes + 255) / 256) * 256;
        return p;
    };
    u16*   Ahi     = (u16*)  carve((size_t)N * DD * 2);
    u8*    Alo     = (u8*)   carve((size_t)N * DD);
    u16*   Bhi     = (u16*)  carve((size_t)N * DD * 2);
    u8*    Blo     = (u8*)   carve((size_t)N * DD);
    short* NRm     = (short*)carve((size_t)N * DD * 2);
    float* NRscale = (float*)carve((size_t)N * 4);
    float* vnBuf   = (float*)carve((size_t)NGRAPH * DD * 4);
    float* vtmpBuf = (float*)carve((size_t)NGRAPH * DD * 4);
    float* repBuf  = (float*)carve((size_t)NGRAPH * DD * 4);
    float* gateBuf = (float*)carve((size_t)N * 4);
    int*   batch32 = (int*)  carve((size_t)N * 4);
    int*   row_ptr = (int*)  carve(((size_t)N + 1) * 4);
    int*   cursor  = (int*)  carve((size_t)N * 4);
    int*   col_idx = (int*)  carve((size_t)E * 4);
    short* W1f     = (short*)carve((size_t)NLAYER * W1F_SZ * 2);
    short* W2f     = (short*)carve((size_t)NLAYER * W1F_SZ * 2);
    short* gW1f    = (short*)carve((size_t)W1F_SZ * 2);

    if (off > ws_size) {
        diag_kernel<<<(out_size + 255) / 256, 256, 0, stream>>>(out, out_size, (float)ws_size);
        return;
    }

    // ---- weight packing ----
    const int pkBlocks = (NT2 * NK2 * 64 + 255) / 256;
    for (int l = 0; l < NLAYER; ++l) {
        packW_kernel<<<pkBlocks, 256, 0, stream>>>(cW1 + (size_t)l * DD * DD2, DD, DD2,
                                                   NT2, NK2, W1f + (size_t)l * W1F_SZ);
        packW_kernel<<<pkBlocks, 256, 0, stream>>>(cW2 + (size_t)l * DD2 * DD, DD2, DD,
                                                   NT3, NK3, W2f + (size_t)l * W1F_SZ);
    }
    packW_kernel<<<pkBlocks, 256, 0, stream>>>(gW1, DD, DD2, NT2, NK2, gW1f);

    bconv_kernel<<<(N + 255) / 256, 256, 0, stream>>>(braw, N, batch32);

    (void)hipMemsetAsync(cursor, 0, (size_t)N * 4, stream);
    deg_kernel<<<(E + 255) / 256, 256, 0, stream>>>(ei, fe, E, cursor);
    scan_kernel<<<1, 1024, 0, stream>>>(cursor, row_ptr, N);
    (void)hipMemcpyAsync(cursor, row_ptr, (size_t)N * 4, hipMemcpyDeviceToDevice, stream);
    scatter_kernel<<<(E + 255) / 256, 256, 0, stream>>>(ei, fe, E, cursor, col_idx);

    vn_init_kernel<<<(NGRAPH * DD + 255) / 256, 256, 0, stream>>>(vnBuf, vn0);

    const int nblk32 = (N + BR - 1) / BR;
    const int nblkM  = (N + BRM - 1) / BRM;
    const int nblk4  = (N + 3) / 4;

    encoder_kernel<<<nblk32, 1024, 0, stream>>>(x, enc_W, enc_b, Ahi, Alo, NRm, NRscale, N);

    u16 *Phi = Ahi, *Qhi = Bhi; u8 *Plo = Alo, *Qlo = Blo;
    for (int l = 0; l < NLAYER; ++l) {
        const bool hasVn = (l < NLAYER - 1);
        const int vnBlocks = hasVn ? NGRAPH : 0;
        agg_vn_kernel<<<nblk4 + vnBlocks, 256, 0, stream>>>(
            Phi, Plo, Qhi, Qlo, row_ptr, col_idx, eps, l, N,
            vnBlocks, batch32,
            vW1 + (size_t)l * DD * DD2, vb1 + (size_t)l * DD2,
            vbn1_s + (size_t)l * DD2, vbn1_b + (size_t)l * DD2,
            vW2 + (size_t)l * DD2 * DD, vb2 + (size_t)l * DD,
            vbn2_s + (size_t)l * DD, vbn2_b + (size_t)l * DD,
            vnBuf);
        mlp_kernel<<<nblkM, 512, 0, stream>>>(
            Qhi, Qlo, NRm, NRscale,
            W1f + (size_t)l * W1F_SZ, cb1 + (size_t)l * DD2,
            cbn_s + (size_t)l * DD2, cbn_b + (size_t)l * DD2,
            W2f + (size_t)l * W1F_SZ, cb2 + (size_t)l * DD,
            bn_s + (size_t)l * DD, bn_b + (size_t)l * DD,
            hasVn ? 1 : 0,
            hasVn ? vnBuf : (const float*)nullptr, batch32,
            hasVn ? 1 : 0, N);
        u16* th = Phi; Phi = Qhi; Qhi = th;
        u8*  tb = Plo; Plo = Qlo; Qlo = tb;
    }

    gate_kernel<<<nblkM, 512, 0, stream>>>(NRm, NRscale, gW1f, gb1, gbn_s, gbn_b,
                                           gW2, gb2, gateBuf, N);
    attn_pool_kernel<<<NGRAPH, 320, 0, stream>>>(gateBuf, NRm, NRscale, batch32, repBuf, N);
    final_kernel<<<NGRAPH, 64, 0, stream>>>(repBuf, pW, pb, out);
}